// Round 4
// baseline (1056.821 us; speedup 1.0000x reference)
//
#include <hip/hip_runtime.h>
#include <hip/hip_bf16.h>
#include <math.h>

#define N_NODES 100000
#define N_EDGES 1600000
#define N_REL   500
#define DIM     128
#define NHEAD   8
#define DFF     512
#define ALPHA   0.15f
#define SLOPE   0.2f
#define LN_EPS  1e-5f

#define SCHUNK   1024
#define NSCANBLK ((N_NODES + SCHUNK - 1) / SCHUNK)   // 98

// windowed scatter: 8 windows of 12500 nodes; 256 edge chunks of 6250
#define NWIN    8
#define WNODES  12500
#define NECHUNK 256
#define ECHUNK  (N_EDGES / NECHUNK)   // 6250

typedef unsigned short u16;
typedef unsigned int   u32;

typedef __attribute__((ext_vector_type(8))) short  bf16x8;   // MFMA A/B frag
typedef __attribute__((ext_vector_type(4))) float  f32x4;    // MFMA C/D frag

__device__ __forceinline__ float bf2f(u16 u) {
    return __uint_as_float(((u32)u) << 16);
}
__device__ __forceinline__ u16 f2bf(float f) {
    __hip_bfloat16 b = __float2bfloat16(f);
    return *reinterpret_cast<u16*>(&b);
}

// paired bf16 extraction: 1 VALU + 1 FMA per element
__device__ __forceinline__ void fma_row(float* acc, float a, const bf16x8& r) {
    const u32* w = (const u32*)&r;
#pragma unroll
    for (int jj = 0; jj < 4; ++jj) {
        acc[2 * jj]     += a * __uint_as_float(w[jj] << 16);
        acc[2 * jj + 1] += a * __uint_as_float(w[jj] & 0xffff0000u);
    }
}

// ---------------- zero an int buffer (graph-capture-safe memset) ------------
__global__ void zero_k(int* __restrict__ p, int n) {
    int i = blockIdx.x * blockDim.x + threadIdx.x;
    if (i < n) p[i] = 0;
}

// ------ weight pre-swizzles to bf16, k-contiguous [n][k] --------------------
__global__ void swz1_k(const float* __restrict__ W1, u16* __restrict__ W1s) {
    const int i = blockIdx.x * 256 + threadIdx.x;       // 65536
    const int k = i >> 9, n = i & 511;
    W1s[n * DIM + k] = f2bf(W1[i]);
}
__global__ void swz2_k(const float* __restrict__ W2, u16* __restrict__ W2s) {
    const int i = blockIdx.x * 256 + threadIdx.x;       // 65536
    const int k = i >> 7, n = i & 127;
    W2s[n * DFF + k] = f2bf(W2[i]);
}
__global__ void swze_k(const float* __restrict__ W, u16* __restrict__ Ws) {
    const int i = blockIdx.x * 256 + threadIdx.x;       // 16384
    const int k = i >> 7, n = i & 127;
    Ws[n * DIM + k] = f2bf(W[i]);
}

// ---------------- LayerNorm 1 : h = LN(ent_feat)  (fp32 in/out) -------------
__global__ __launch_bounds__(128) void ln1_k(const float* __restrict__ x,
        const float* __restrict__ g, const float* __restrict__ b,
        float* __restrict__ h) {
    const int n = blockIdx.x, t = threadIdx.x;
    const float v = x[n * DIM + t];
    float s = v, q = v * v;
#pragma unroll
    for (int off = 32; off > 0; off >>= 1) {
        s += __shfl_xor(s, off, 64);
        q += __shfl_xor(q, off, 64);
    }
    __shared__ float ss[2], qq[2];
    if ((t & 63) == 0) { ss[t >> 6] = s; qq[t >> 6] = q; }
    __syncthreads();
    s = ss[0] + ss[1]; q = qq[0] + qq[1];
    const float mu  = s * (1.0f / 128.0f);
    const float var = q * (1.0f / 128.0f) - mu * mu;
    const float rs  = rsqrtf(fmaxf(var, 0.f) + LN_EPS);
    h[n * DIM + t] = (v - mu) * rs * g[t] + b[t];
}

// --------- feat0 = h @ W_ent via MFMA bf16 (32 nodes/block, 4 waves) --------
#define HP 136   // hsb row pitch (u16), 136 = 8*17 (keeps 16B frag alignment)
__global__ __launch_bounds__(256) void proj_k(const float* __restrict__ h,
        const u16* __restrict__ Wes,  // [DIM n][DIM k] bf16, k-contig
        u16* __restrict__ feat0) {
    __shared__ u16 hsb[32 * HP];
    const int t   = threadIdx.x;
    const int n0b = blockIdx.x * 32;

    // stage h (fp32 -> bf16) into LDS: thread t -> row t>>3, 16 cols
    {
        const int sr = t >> 3;
        const int sc = (t & 7) * 16;
        const float* hrow = &h[(size_t)(n0b + sr) * DIM + sc];
        u16* drow = &hsb[sr * HP + sc];
#pragma unroll
        for (int i = 0; i < 4; ++i) {
            const float4 hv = ((const float4*)hrow)[i];
            ushort4 o;
            o.x = f2bf(hv.x); o.y = f2bf(hv.y); o.z = f2bf(hv.z); o.w = f2bf(hv.w);
            ((ushort4*)drow)[i] = o;
        }
    }
    __syncthreads();

    const int wv   = t >> 6;
    const int lane = t & 63;
    const int lm   = lane & 15;
    const int q4   = lane >> 4;
    const int mrow = (wv & 1) * 16;        // rows [mrow, mrow+16)
    const int chalf = (wv >> 1) * 64;      // cols [chalf, chalf+64)

    bf16x8 afr[4];
#pragma unroll
    for (int kt = 0; kt < 4; ++kt)
        afr[kt] = *(const bf16x8*)&hsb[(mrow + lm) * HP + kt * 32 + q4 * 8];

#pragma unroll
    for (int nt = 0; nt < 4; ++nt) {
        const int c0 = chalf + nt * 16;
        f32x4 acc = {0.f, 0.f, 0.f, 0.f};
#pragma unroll
        for (int kt = 0; kt < 4; ++kt) {
            const bf16x8 bfr = *(const bf16x8*)&Wes[(c0 + lm) * DIM + kt * 32 + q4 * 8];
            acc = __builtin_amdgcn_mfma_f32_16x16x32_bf16(afr[kt], bfr, acc, 0, 0, 0);
        }
#pragma unroll
        for (int r = 0; r < 4; ++r)
            feat0[(size_t)(n0b + mrow + q4 * 4 + r) * DIM + c0 + lm] = f2bf(acc[r]);
    }
}

// --------- eh/et: per-head attn dots from feat0 -----------------------------
__global__ __launch_bounds__(256) void eh_k(const u16* __restrict__ feat0,
        const float* __restrict__ attn_h, const float* __restrict__ attn_t,
        float* __restrict__ eh, float* __restrict__ et) {
    __shared__ float ahs[DIM], ats[DIM];
    const int t = threadIdx.x;
    if (t < DIM) { ahs[t] = attn_h[t]; ats[t] = attn_t[t]; }
    __syncthreads();
    const int idx  = blockIdx.x * 256 + t;
    const int n    = idx >> 3;
    const int head = idx & 7;
    const u16* fp = &feat0[(size_t)n * DIM + head * 16];
    float sh = 0.f, st = 0.f;
#pragma unroll
    for (int i = 0; i < 4; ++i) {
        const ushort4 f4 = ((const ushort4*)fp)[i];
        const int c = head * 16 + i * 4;
        sh += bf2f(f4.x) * ahs[c+0] + bf2f(f4.y) * ahs[c+1]
            + bf2f(f4.z) * ahs[c+2] + bf2f(f4.w) * ahs[c+3];
        st += bf2f(f4.x) * ats[c+0] + bf2f(f4.y) * ats[c+1]
            + bf2f(f4.z) * ats[c+2] + bf2f(f4.w) * ats[c+3];
    }
    eh[idx] = sh;
    et[idx] = st;
}

// ---------------- er[r][head] = ((rel_feat @ W_rel) * attn_r).sum ----------
__global__ __launch_bounds__(128) void rel_k(const float* __restrict__ rel_feat,
        const float* __restrict__ W,
        const float* __restrict__ attn_r, float* __restrict__ er) {
    __shared__ float rf[DIM];
    __shared__ float pr[DIM];
    const int r = blockIdx.x, t = threadIdx.x;
    rf[t] = rel_feat[r * DIM + t];
    __syncthreads();
    float acc = 0.f;
    for (int d = 0; d < DIM; ++d) acc += rf[d] * W[d * DIM + t];
    pr[t] = acc * attn_r[t];
    __syncthreads();
    if (t < NHEAD) {
        float s = 0.f;
        for (int i = 0; i < 16; ++i) s += pr[t * 16 + i];
        er[r * NHEAD + t] = s;
    }
}

// ---------------- CSR build: histogram, 3-phase scan, scatter ---------------
__global__ void count_k(const int* __restrict__ dst, int* __restrict__ counts) {
    int e = blockIdx.x * blockDim.x + threadIdx.x;
    if (e < N_EDGES) atomicAdd(&counts[dst[e]], 1);
}

__global__ __launch_bounds__(256) void scan1_k(const int* __restrict__ counts,
        int* __restrict__ offsets, int* __restrict__ blk_sums, int n) {
    __shared__ int wsum[4];
    const int t = threadIdx.x, lane = t & 63, wid = t >> 6;
    const int base = blockIdx.x * SCHUNK + t * 4;
    int v0 = 0, v1 = 0, v2 = 0, v3 = 0;
    if (base + 3 < n) {
        const int4 c4 = *(const int4*)&counts[base];
        v0 = c4.x; v1 = c4.y; v2 = c4.z; v3 = c4.w;
    } else {
        if (base + 0 < n) v0 = counts[base + 0];
        if (base + 1 < n) v1 = counts[base + 1];
        if (base + 2 < n) v2 = counts[base + 2];
        if (base + 3 < n) v3 = counts[base + 3];
    }
    const int s4 = v0 + v1 + v2 + v3;
    int incl = s4;
#pragma unroll
    for (int off = 1; off < 64; off <<= 1) {
        const int tt = __shfl_up(incl, off, 64);
        if (lane >= off) incl += tt;
    }
    if (lane == 63) wsum[wid] = incl;
    __syncthreads();
    int wbase = 0;
#pragma unroll
    for (int w = 0; w < 4; ++w) if (w < wid) wbase += wsum[w];
    const int excl = wbase + incl - s4;
    if (base + 0 < n) offsets[base + 0] = excl;
    if (base + 1 < n) offsets[base + 1] = excl + v0;
    if (base + 2 < n) offsets[base + 2] = excl + v0 + v1;
    if (base + 3 < n) offsets[base + 3] = excl + v0 + v1 + v2;
    if (t == 255) blk_sums[blockIdx.x] = wbase + incl;
}

__global__ __launch_bounds__(128) void scan2_k(const int* __restrict__ blk_sums,
        int* __restrict__ blk_off, int* __restrict__ offsets, int nblk, int n) {
    const int t = threadIdx.x;
    const int v = (t < nblk) ? blk_sums[t] : 0;
    int incl = v;
#pragma unroll
    for (int off = 1; off < 64; off <<= 1) {
        const int tt = __shfl_up(incl, off, 64);
        if ((t & 63) >= off) incl += tt;
    }
    __shared__ int w0sum;
    if (t == 63) w0sum = incl;
    __syncthreads();
    int x = incl - v;
    if (t >= 64) x += w0sum;
    if (t < nblk) blk_off[t] = x;
    if (t == nblk - 1) offsets[n] = x + v;
}

__global__ __launch_bounds__(256) void scan3_k(int* __restrict__ offsets,
        int* __restrict__ cursor, const int* __restrict__ blk_off, int n) {
    const int add  = blk_off[blockIdx.x];
    const int base = blockIdx.x * SCHUNK + threadIdx.x * 4;
#pragma unroll
    for (int j = 0; j < 4; ++j) {
        const int i = base + j;
        if (i < n) {
            const int o = offsets[i] + add;
            offsets[i] = o;
            cursor[i]  = o;
        }
    }
}

// windowed scatter: block b handles dst-window (b&7) over edge chunk (b>>3).
__global__ __launch_bounds__(256) void scatter_k(const int* __restrict__ src,
        const int* __restrict__ dst, const int* __restrict__ etype,
        int* __restrict__ cursor, u32* __restrict__ csr_se) {
    const int b  = blockIdx.x;          // 2048 blocks
    const int w  = b & (NWIN - 1);
    const int r  = b >> 3;
    const int lo = w * WNODES, hi = lo + WNODES;
    const int base = r * ECHUNK;
    for (int i = threadIdx.x; i < ECHUNK; i += 256) {
        const int e = base + i;
        const int d = dst[e];
        if (d >= lo && d < hi) {
            const int s   = src[e];
            const int rel = etype[e];
            const int pos = atomicAdd(&cursor[d], 1);
            if (pos >= 0 && pos < N_EDGES)
                csr_se[pos] = (u32)s | ((u32)rel << 17);
        }
    }
}

// --------- edge softmax: scores on the fly, first-4 cached in registers ----
// 4 nodes per 256-thread block (1 wave/node); lane -> (slot=lane/8, head=lane%8)
__global__ __launch_bounds__(256) void softmax_k(const int* __restrict__ offsets,
        const u32* __restrict__ csr_se,
        const float* __restrict__ eh, const float* __restrict__ et,
        const float* __restrict__ er,
        u16* __restrict__ csr_ab, float* __restrict__ inv_buf) {
    const int n = blockIdx.x * 4 + (threadIdx.x >> 6);
    const int beg = offsets[n], end = offsets[n + 1];
    const int lane = threadIdx.x & 63;
    const int k  = lane & 7;
    const int eo = lane >> 3;
    const float etk = et[n * NHEAD + k];

    auto score = [&](int e) -> float {
        const u32 se = csr_se[e];
        const int s = se & 0x1FFFF;
        const int r = se >> 17;
        float sc = eh[s * NHEAD + k] + etk + er[r * NHEAD + k];
        return sc > 0.f ? sc : SLOPE * sc;
    };

    const int e0 = beg + eo;
    float c0 = 0.f, c1 = 0.f, c2 = 0.f, c3 = 0.f;
    float m = -1e30f;
    if (e0 < end)      { c0 = score(e0);      m = fmaxf(m, c0); }
    if (e0 + 8 < end)  { c1 = score(e0 + 8);  m = fmaxf(m, c1); }
    if (e0 + 16 < end) { c2 = score(e0 + 16); m = fmaxf(m, c2); }
    if (e0 + 24 < end) { c3 = score(e0 + 24); m = fmaxf(m, c3); }
    for (int e = e0 + 32; e < end; e += 8) m = fmaxf(m, score(e));
    m = fmaxf(m, __shfl_xor(m, 8, 64));
    m = fmaxf(m, __shfl_xor(m, 16, 64));
    m = fmaxf(m, __shfl_xor(m, 32, 64));

    float ssum = 0.f;
    if (e0 < end)      { const float ex = expf(c0 - m);
                         csr_ab[(size_t)e0 * NHEAD + k] = f2bf(ex); ssum += ex; }
    if (e0 + 8 < end)  { const float ex = expf(c1 - m);
                         csr_ab[(size_t)(e0 + 8) * NHEAD + k] = f2bf(ex); ssum += ex; }
    if (e0 + 16 < end) { const float ex = expf(c2 - m);
                         csr_ab[(size_t)(e0 + 16) * NHEAD + k] = f2bf(ex); ssum += ex; }
    if (e0 + 24 < end) { const float ex = expf(c3 - m);
                         csr_ab[(size_t)(e0 + 24) * NHEAD + k] = f2bf(ex); ssum += ex; }
    for (int e = e0 + 32; e < end; e += 8) {
        const float ex = expf(score(e) - m);
        csr_ab[(size_t)e * NHEAD + k] = f2bf(ex);
        ssum += ex;
    }
    ssum += __shfl_xor(ssum, 8, 64);
    ssum += __shfl_xor(ssum, 16, 64);
    ssum += __shfl_xor(ssum, 32, 64);
    const float inv = 1.f / fmaxf(ssum, 1e-20f);
    if (lane < 8) inv_buf[n * NHEAD + lane] = inv;
}

// ---------------- one PPR diffusion hop (bf16 f, bf16 a, deferred norm) ----
// wave per node; 16 lanes x 16B cover one 256B row; 4 edges batched per tile.
// Lean register budget: launch_bounds(256,8) -> VGPR<=64 -> 8 waves/SIMD.
__global__ __launch_bounds__(256, 8) void hop_k(const u16* __restrict__ f_in,
        u16* __restrict__ f_out, const u16* __restrict__ feat0,
        const int* __restrict__ offsets, const u32* __restrict__ csr_se,
        const u16* __restrict__ csr_ab, const float* __restrict__ inv_buf) {
    const int n    = blockIdx.x * 4 + (threadIdx.x >> 6);
    const int lane = threadIdx.x & 63;
    const int li   = lane & 15;     // position within a 256B row (16B each)
    const int grp  = lane >> 4;     // which of 4 concurrent edges
    const int hsel = li >> 1;       // head owning this lane's 8 dims
    const int beg = offsets[n], end = offsets[n + 1];

    float acc[8];
#pragma unroll
    for (int j = 0; j < 8; ++j) acc[j] = 0.f;

    for (int e0 = beg; e0 < end; e0 += 16) {
        const u32 se16 = csr_se[min(e0 + li, end - 1)];
        const int s0 = (int)(__shfl(se16, grp,      16) & 0x1FFFF);
        const int s1 = (int)(__shfl(se16, 4 + grp,  16) & 0x1FFFF);
        const int s2 = (int)(__shfl(se16, 8 + grp,  16) & 0x1FFFF);
        const int s3 = (int)(__shfl(se16, 12 + grp, 16) & 0x1FFFF);
        if (e0 + 16 <= end) {
            // full tile: 4 batched gathers, no masks
            const bf16x8 r0 = *(const bf16x8*)&f_in[(size_t)s0 * DIM + li * 8];
            const bf16x8 r1 = *(const bf16x8*)&f_in[(size_t)s1 * DIM + li * 8];
            const bf16x8 r2 = *(const bf16x8*)&f_in[(size_t)s2 * DIM + li * 8];
            const bf16x8 r3 = *(const bf16x8*)&f_in[(size_t)s3 * DIM + li * 8];
            const float a0 = bf2f(csr_ab[(size_t)(e0 + grp)      * NHEAD + hsel]);
            const float a1 = bf2f(csr_ab[(size_t)(e0 + 4 + grp)  * NHEAD + hsel]);
            const float a2 = bf2f(csr_ab[(size_t)(e0 + 8 + grp)  * NHEAD + hsel]);
            const float a3 = bf2f(csr_ab[(size_t)(e0 + 12 + grp) * NHEAD + hsel]);
            fma_row(acc, a0, r0);
            fma_row(acc, a1, r1);
            fma_row(acc, a2, r2);
            fma_row(acc, a3, r3);
        } else {
            // masked tail tile: loads batched under per-edge predicates
            const int rem = end - e0;
            bf16x8 r0 = {}, r1 = {}, r2 = {}, r3 = {};
            float a0 = 0.f, a1 = 0.f, a2 = 0.f, a3 = 0.f;
            if (grp < rem)      { r0 = *(const bf16x8*)&f_in[(size_t)s0 * DIM + li * 8];
                                  a0 = bf2f(csr_ab[(size_t)(e0 + grp)      * NHEAD + hsel]); }
            if (grp + 4 < rem)  { r1 = *(const bf16x8*)&f_in[(size_t)s1 * DIM + li * 8];
                                  a1 = bf2f(csr_ab[(size_t)(e0 + 4 + grp)  * NHEAD + hsel]); }
            if (grp + 8 < rem)  { r2 = *(const bf16x8*)&f_in[(size_t)s2 * DIM + li * 8];
                                  a2 = bf2f(csr_ab[(size_t)(e0 + 8 + grp)  * NHEAD + hsel]); }
            if (grp + 12 < rem) { r3 = *(const bf16x8*)&f_in[(size_t)s3 * DIM + li * 8];
                                  a3 = bf2f(csr_ab[(size_t)(e0 + 12 + grp) * NHEAD + hsel]); }
            fma_row(acc, a0, r0);
            fma_row(acc, a1, r1);
            fma_row(acc, a2, r2);
            fma_row(acc, a3, r3);
        }
    }
#pragma unroll
    for (int j = 0; j < 8; ++j) {
        acc[j] += __shfl_xor(acc[j], 16, 64);
        acc[j] += __shfl_xor(acc[j], 32, 64);
    }
    if (lane < 16) {
        const float iv = inv_buf[n * NHEAD + hsel];
        const bf16x8 p = *(const bf16x8*)&feat0[(size_t)n * DIM + li * 8];
        bf16x8 o;
#pragma unroll
        for (int j = 0; j < 8; ++j)
            o[j] = (short)f2bf((1.f - ALPHA) * acc[j] * iv + ALPHA * bf2f((u16)p[j]));
        *(bf16x8*)&f_out[(size_t)n * DIM + li * 8] = o;
    }
}

// ---------------- FFN sublayer via MFMA bf16 + residuals, fp32 out ---------
// 2 barriers total; per-wave LN (no LDS reduce); prefetched weight frags.
#define YP 136
#define ZP 520
__global__ __launch_bounds__(256) void ffn_k(const u16* __restrict__ f,
        const float* __restrict__ h,
        const float* __restrict__ g2, const float* __restrict__ b2ln,
        const u16* __restrict__ W1s,  // [DFF][DIM] bf16, k-contig
        const float* __restrict__ b1,
        const u16* __restrict__ W2s,  // [DIM][DFF] bf16, k-contig
        const float* __restrict__ b2,
        float* __restrict__ out) {
    __shared__ u16 ysb[32 * YP];
    __shared__ u16 zsb[32 * ZP];

    const int t    = threadIdx.x;
    const int n0b  = blockIdx.x * 32;
    const int wv   = t >> 6;
    const int lane = t & 63;

    // Phase A: per-wave LN of 8 nodes (wave wv -> nodes wv*8..wv*8+7);
    // each node uses 8 lanes x 16 dims; reduce via intra-8-lane shuffles.
    {
        const int nl   = lane >> 3;              // 0..7 node within wave
        const int node = wv * 8 + nl;
        const int cp   = (lane & 7) * 16;        // dim chunk base
        const int gbase = (n0b + node) * DIM + cp;
        float rv[16];
#pragma unroll
        for (int i = 0; i < 4; ++i) {
            const ushort4 fu = *(const ushort4*)&f[gbase + i * 4];
            const float4  hv = *(const float4*)&h[gbase + i * 4];
            rv[i * 4 + 0] = bf2f(fu.x) + hv.x;
            rv[i * 4 + 1] = bf2f(fu.y) + hv.y;
            rv[i * 4 + 2] = bf2f(fu.z) + hv.z;
            rv[i * 4 + 3] = bf2f(fu.w) + hv.w;
        }
        float s = 0.f, q = 0.f;
#pragma unroll
        for (int i = 0; i < 16; ++i) { s += rv[i]; q += rv[i] * rv[i]; }
        s += __shfl_xor(s, 1, 64); q += __shfl_xor(q, 1, 64);
        s += __shfl_xor(s, 2, 64); q += __shfl_xor(q, 2, 64);
        s += __shfl_xor(s, 4, 64); q += __shfl_xor(q, 4, 64);
        const float mu  = s * (1.0f / 128.0f);
        const float var = q * (1.0f / 128.0f) - mu * mu;
        const float rs  = rsqrtf(fmaxf(var, 0.f) + LN_EPS);
#pragma unroll
        for (int i = 0; i < 4; ++i) {
            ushort4 yo;
            const int c = cp + i * 4;
            yo.x = f2bf((rv[i*4+0] - mu) * rs * g2[c+0] + b2ln[c+0]);
            yo.y = f2bf((rv[i*4+1] - mu) * rs * g2[c+1] + b2ln[c+1]);
            yo.z = f2bf((rv[i*4+2] - mu) * rs * g2[c+2] + b2ln[c+2]);
            yo.w = f2bf((rv[i*4+3] - mu) * rs * g2[c+3] + b2ln[c+3]);
            *(ushort4*)&ysb[node * YP + c] = yo;
        }
    }
    __syncthreads();

    const int lm = lane & 15;
    const int q4 = lane >> 4;

    // Phase B: z = relu(y @ W1), wave wv -> z-cols [wv*128, wv*128+128)
    {
        bf16x8 afr[2][4];
#pragma unroll
        for (int mt = 0; mt < 2; ++mt)
#pragma unroll
            for (int kt = 0; kt < 4; ++kt)
                afr[mt][kt] = *(const bf16x8*)&ysb[(mt * 16 + lm) * YP + kt * 32 + q4 * 8];

        const int cw = wv * 128;
        bf16x8 bc[4];
#pragma unroll
        for (int kt = 0; kt < 4; ++kt)
            bc[kt] = *(const bf16x8*)&W1s[(cw + lm) * DIM + kt * 32 + q4 * 8];

#pragma unroll
        for (int nt = 0; nt < 8; ++nt) {
            const int n0 = cw + nt * 16;
            bf16x8 bn[4] = {bc[0], bc[1], bc[2], bc[3]};
            if (nt < 7) {
#pragma unroll
                for (int kt = 0; kt < 4; ++kt)
                    bn[kt] = *(const bf16x8*)&W1s[(n0 + 16 + lm) * DIM + kt * 32 + q4 * 8];
            }
            f32x4 acc0 = {0.f, 0.f, 0.f, 0.f};
            f32x4 acc1 = {0.f, 0.f, 0.f, 0.f};
#pragma unroll
            for (int kt = 0; kt < 4; ++kt) {
                acc0 = __builtin_amdgcn_mfma_f32_16x16x32_bf16(afr[0][kt], bc[kt], acc0, 0, 0, 0);
                acc1 = __builtin_amdgcn_mfma_f32_16x16x32_bf16(afr[1][kt], bc[kt], acc1, 0, 0, 0);
            }
            const float bias = b1[n0 + lm];
#pragma unroll
            for (int r = 0; r < 4; ++r) {
                zsb[(q4 * 4 + r) * ZP + n0 + lm]      = f2bf(fmaxf(acc0[r] + bias, 0.f));
                zsb[(16 + q4 * 4 + r) * ZP + n0 + lm] = f2bf(fmaxf(acc1[r] + bias, 0.f));
            }
#pragma unroll
            for (int kt = 0; kt < 4; ++kt) bc[kt] = bn[kt];
        }
    }
    __syncthreads();

    // Phase C: out = z @ W2 (+bias +residuals), wave wv -> out-cols [wv*32,+32)
    f32x4 acc[2][2];
#pragma unroll
    for (int i = 0; i < 2; ++i)
#pragma unroll
        for (int j = 0; j < 2; ++j)
            acc[i][j] = (f32x4){0.f, 0.f, 0.f, 0.f};
    const int c0 = wv * 32;
    bf16x8 wc0 = *(const bf16x8*)&W2s[(c0 + lm) * DFF + q4 * 8];
    bf16x8 wc1 = *(const bf16x8*)&W2s[(c0 + 16 + lm) * DFF + q4 * 8];
#pragma unroll
    for (int kt = 0; kt < 16; ++kt) {
        bf16x8 wn0 = wc0, wn1 = wc1;
        if (kt < 15) {
            wn0 = *(const bf16x8*)&W2s[(c0 + lm) * DFF + (kt + 1) * 32 + q4 * 8];
            wn1 = *(const bf16x8*)&W2s[(c0 + 16 + lm) * DFF + (kt + 1) * 32 + q4 * 8];
        }
        const bf16x8 a0 = *(const bf16x8*)&zsb[(lm) * ZP + kt * 32 + q4 * 8];
        const bf16x8 a1 = *(const bf16x8*)&zsb[(16 + lm) * ZP + kt * 32 + q4 * 8];
        acc[0][0] = __builtin_amdgcn_mfma_f32_16x16x32_bf16(a0, wc0, acc[0][0], 0, 0, 0);
        acc[0][1] = __builtin_amdgcn_mfma_f32_16x16x32_bf16(a0, wc1, acc[0][1], 0, 0, 0);
        acc[1][0] = __builtin_amdgcn_mfma_f32_16x16x32_bf16(a1, wc0, acc[1][0], 0, 0, 0);
        acc[1][1] = __builtin_amdgcn_mfma_f32_16x16x32_bf16(a1, wc1, acc[1][1], 0, 0, 0);
        wc0 = wn0; wc1 = wn1;
    }

#pragma unroll
    for (int ntile = 0; ntile < 2; ++ntile) {
        const int col = c0 + ntile * 16 + lm;
        const float bias = b2[col];
#pragma unroll
        for (int mt = 0; mt < 2; ++mt) {
#pragma unroll
            for (int r = 0; r < 4; ++r) {
                const int row  = mt * 16 + q4 * 4 + r;
                const int gidx = (n0b + row) * DIM + col;
                out[gidx] = acc[mt][ntile][r] + bias + bf2f(f[gidx]) + h[gidx];
            }
        }
    }
}

// ---------------------------------------------------------------------------
extern "C" void kernel_launch(void* const* d_in, const int* in_sizes, int n_in,
                              void* d_out, int out_size, void* d_ws, size_t ws_size,
                              hipStream_t stream) {
    const float* ent_feat = (const float*)d_in[0];
    const float* rel_feat = (const float*)d_in[1];
    const int*   src      = (const int*)d_in[2];
    const int*   dst      = (const int*)d_in[3];
    const int*   e_type   = (const int*)d_in[4];
    const float* ln1_g    = (const float*)d_in[5];
    const float* ln1_b    = (const float*)d_in[6];
    const float* W_ent    = (const float*)d_in[7];
    const float* W_rel    = (const float*)d_in[8];
    const float* attn_h   = (const float*)d_in[9];
    const float* attn_t   = (const float*)d_in[10];
    const float* attn_r   = (const float*)d_in[11];
    const float* ln2_g    = (const float*)d_in[12];
    const float* ln2_b    = (const float*)d_in[13];
    const float* W1       = (const float*)d_in[14];
    const float* b1       = (const float*)d_in[15];
    const float* W2       = (const float*)d_in[16];
    const float* b2       = (const float*)d_in[17];
    float* out = (float*)d_out;

    char* ws = (char*)d_ws;
    size_t used = 0;
    auto alloc = [&](size_t bytes) -> char* {
        char* p = ws + used;
        used += (bytes + 255) & ~(size_t)255;
        return p;
    };
    float* h       = (float*)alloc((size_t)N_NODES * DIM * 4);   // 51.2 MB
    u16*   feat0   = (u16*)  alloc((size_t)N_NODES * DIM * 2);   // 25.6 MB
    u16*   fA      = (u16*)  alloc((size_t)N_NODES * DIM * 2);   // 25.6 MB
    u16*   fB      = (u16*)  alloc((size_t)N_NODES * DIM * 2);   // 25.6 MB
    u16*   csr_ab  = (u16*)  alloc((size_t)N_EDGES * NHEAD * 2); // 25.6 MB
    float* eh      = (float*)alloc((size_t)N_NODES * NHEAD * 4); // 3.2 MB
    float* et      = (float*)alloc((size_t)N_NODES * NHEAD * 4); // 3.2 MB
    float* inv_buf = (float*)alloc((size_t)N_NODES * NHEAD * 4); // 3.2 MB
    u32*   csr_se  = (u32*)  alloc((size_t)N_EDGES * 4);         // 6.4 MB
    int*   counts  = (int*)  alloc((size_t)N_NODES * 4);
    int*   offsets = (int*)  alloc((size_t)(N_NODES + 1) * 4);
    int*   cursor  = (int*)  alloc((size_t)N_NODES * 4);
    float* er      = (float*)alloc((size_t)N_REL * NHEAD * 4);
    u16*   W1s     = (u16*)  alloc((size_t)DIM * DFF * 2);
    u16*   W2s     = (u16*)  alloc((size_t)DFF * DIM * 2);
    u16*   Wes     = (u16*)  alloc((size_t)DIM * DIM * 2);
    int*   blk_sums= (int*)  alloc((size_t)NSCANBLK * 4);
    int*   blk_off = (int*)  alloc((size_t)NSCANBLK * 4);

    if (used > ws_size) return;   // diagnostic: absmax == max|ref|

    swz1_k<<<DIM * DFF / 256, 256, 0, stream>>>(W1, W1s);
    swz2_k<<<DFF * DIM / 256, 256, 0, stream>>>(W2, W2s);
    swze_k<<<DIM * DIM / 256, 256, 0, stream>>>(W_ent, Wes);

    ln1_k<<<N_NODES, 128, 0, stream>>>(ent_feat, ln1_g, ln1_b, h);
    proj_k<<<N_NODES / 32, 256, 0, stream>>>(h, Wes, feat0);
    eh_k<<<N_NODES * NHEAD / 256, 256, 0, stream>>>(feat0, attn_h, attn_t, eh, et);
    rel_k<<<N_REL, 128, 0, stream>>>(rel_feat, W_rel, attn_r, er);

    zero_k<<<(N_NODES + 255) / 256, 256, 0, stream>>>(counts, N_NODES);
    count_k<<<(N_EDGES + 255) / 256, 256, 0, stream>>>(dst, counts);
    scan1_k<<<NSCANBLK, 256, 0, stream>>>(counts, offsets, blk_sums, N_NODES);
    scan2_k<<<1, 128, 0, stream>>>(blk_sums, blk_off, offsets, NSCANBLK, N_NODES);
    scan3_k<<<NSCANBLK, 256, 0, stream>>>(offsets, cursor, blk_off, N_NODES);
    scatter_k<<<NECHUNK * NWIN, 256, 0, stream>>>(src, dst, e_type,
                                                  cursor, csr_se);
    softmax_k<<<N_NODES / 4, 256, 0, stream>>>(offsets, csr_se, eh, et, er,
                                               csr_ab, inv_buf);

    // 5 PPR hops: feat0 -> fA -> fB -> fA -> fB -> fA
    hop_k<<<N_NODES / 4, 256, 0, stream>>>(feat0, fA, feat0, offsets, csr_se, csr_ab, inv_buf);
    hop_k<<<N_NODES / 4, 256, 0, stream>>>(fA, fB, feat0, offsets, csr_se, csr_ab, inv_buf);
    hop_k<<<N_NODES / 4, 256, 0, stream>>>(fB, fA, feat0, offsets, csr_se, csr_ab, inv_buf);
    hop_k<<<N_NODES / 4, 256, 0, stream>>>(fA, fB, feat0, offsets, csr_se, csr_ab, inv_buf);
    hop_k<<<N_NODES / 4, 256, 0, stream>>>(fB, fA, feat0, offsets, csr_se, csr_ab, inv_buf);

    // FFN + residuals (MFMA)
    ffn_k<<<N_NODES / 32, 256, 0, stream>>>(fA, h, ln2_g, ln2_b, W1s, b1, W2s, b2,
                                            out);
}

// Round 5
// 969.763 us; speedup vs baseline: 1.0898x; 1.0898x over previous
//
#include <hip/hip_runtime.h>
#include <hip/hip_bf16.h>
#include <math.h>

#define N_NODES 100000
#define N_EDGES 1600000
#define N_REL   500
#define DIM     128
#define NHEAD   8
#define DFF     512
#define ALPHA   0.15f
#define SLOPE   0.2f
#define LN_EPS  1e-5f

#define SCHUNK   1024
#define NSCANBLK ((N_NODES + SCHUNK - 1) / SCHUNK)   // 98

// windowed scatter: 8 windows of 12500 nodes; 256 edge chunks of 6250
#define NWIN    8
#define WNODES  12500
#define NECHUNK 256
#define ECHUNK  (N_EDGES / NECHUNK)   // 6250

// ffn tile: 16 nodes/block -> ~21KB LDS -> 7 blocks/CU (occupancy fix)
#define FNODES  16

typedef unsigned short u16;
typedef unsigned int   u32;

typedef __attribute__((ext_vector_type(8))) short  bf16x8;   // MFMA A/B frag
typedef __attribute__((ext_vector_type(4))) float  f32x4;    // MFMA C/D frag

__device__ __forceinline__ float bf2f(u16 u) {
    return __uint_as_float(((u32)u) << 16);
}
__device__ __forceinline__ u16 f2bf(float f) {
    __hip_bfloat16 b = __float2bfloat16(f);
    return *reinterpret_cast<u16*>(&b);
}

// ---------------- zero an int buffer (graph-capture-safe memset) ------------
__global__ void zero_k(int* __restrict__ p, int n) {
    int i = blockIdx.x * blockDim.x + threadIdx.x;
    if (i < n) p[i] = 0;
}

// ------ weight pre-swizzles to bf16, k-contiguous [n][k] --------------------
__global__ void swz1_k(const float* __restrict__ W1, u16* __restrict__ W1s) {
    const int i = blockIdx.x * 256 + threadIdx.x;       // 65536
    const int k = i >> 9, n = i & 511;
    W1s[n * DIM + k] = f2bf(W1[i]);
}
__global__ void swz2_k(const float* __restrict__ W2, u16* __restrict__ W2s) {
    const int i = blockIdx.x * 256 + threadIdx.x;       // 65536
    const int k = i >> 7, n = i & 127;
    W2s[n * DFF + k] = f2bf(W2[i]);
}
__global__ void swze_k(const float* __restrict__ W, u16* __restrict__ Ws) {
    const int i = blockIdx.x * 256 + threadIdx.x;       // 16384
    const int k = i >> 7, n = i & 127;
    Ws[n * DIM + k] = f2bf(W[i]);
}

// ---------------- LayerNorm 1 : h = LN(ent_feat)  (fp32 in/out) -------------
__global__ __launch_bounds__(128) void ln1_k(const float* __restrict__ x,
        const float* __restrict__ g, const float* __restrict__ b,
        float* __restrict__ h) {
    const int n = blockIdx.x, t = threadIdx.x;
    const float v = x[n * DIM + t];
    float s = v, q = v * v;
#pragma unroll
    for (int off = 32; off > 0; off >>= 1) {
        s += __shfl_xor(s, off, 64);
        q += __shfl_xor(q, off, 64);
    }
    __shared__ float ss[2], qq[2];
    if ((t & 63) == 0) { ss[t >> 6] = s; qq[t >> 6] = q; }
    __syncthreads();
    s = ss[0] + ss[1]; q = qq[0] + qq[1];
    const float mu  = s * (1.0f / 128.0f);
    const float var = q * (1.0f / 128.0f) - mu * mu;
    const float rs  = rsqrtf(fmaxf(var, 0.f) + LN_EPS);
    h[n * DIM + t] = (v - mu) * rs * g[t] + b[t];
}

// --------- feat0 = h @ W_ent via MFMA bf16 (32 nodes/block, 4 waves) --------
#define HP 136   // hsb row pitch (u16), 136 = 8*17 (keeps 16B frag alignment)
__global__ __launch_bounds__(256) void proj_k(const float* __restrict__ h,
        const u16* __restrict__ Wes,  // [DIM n][DIM k] bf16, k-contig
        u16* __restrict__ feat0) {
    __shared__ u16 hsb[32 * HP];
    const int t   = threadIdx.x;
    const int n0b = blockIdx.x * 32;

    // stage h (fp32 -> bf16) into LDS: thread t -> row t>>3, 16 cols
    {
        const int sr = t >> 3;
        const int sc = (t & 7) * 16;
        const float* hrow = &h[(size_t)(n0b + sr) * DIM + sc];
        u16* drow = &hsb[sr * HP + sc];
#pragma unroll
        for (int i = 0; i < 4; ++i) {
            const float4 hv = ((const float4*)hrow)[i];
            ushort4 o;
            o.x = f2bf(hv.x); o.y = f2bf(hv.y); o.z = f2bf(hv.z); o.w = f2bf(hv.w);
            ((ushort4*)drow)[i] = o;
        }
    }
    __syncthreads();

    const int wv   = t >> 6;
    const int lane = t & 63;
    const int lm   = lane & 15;
    const int q4   = lane >> 4;
    const int mrow = (wv & 1) * 16;        // rows [mrow, mrow+16)
    const int chalf = (wv >> 1) * 64;      // cols [chalf, chalf+64)

    bf16x8 afr[4];
#pragma unroll
    for (int kt = 0; kt < 4; ++kt)
        afr[kt] = *(const bf16x8*)&hsb[(mrow + lm) * HP + kt * 32 + q4 * 8];

#pragma unroll
    for (int nt = 0; nt < 4; ++nt) {
        const int c0 = chalf + nt * 16;
        f32x4 acc = {0.f, 0.f, 0.f, 0.f};
#pragma unroll
        for (int kt = 0; kt < 4; ++kt) {
            const bf16x8 bfr = *(const bf16x8*)&Wes[(c0 + lm) * DIM + kt * 32 + q4 * 8];
            acc = __builtin_amdgcn_mfma_f32_16x16x32_bf16(afr[kt], bfr, acc, 0, 0, 0);
        }
#pragma unroll
        for (int r = 0; r < 4; ++r)
            feat0[(size_t)(n0b + mrow + q4 * 4 + r) * DIM + c0 + lm] = f2bf(acc[r]);
    }
}

// --------- eh/et: per-head attn dots from feat0 -----------------------------
__global__ __launch_bounds__(256) void eh_k(const u16* __restrict__ feat0,
        const float* __restrict__ attn_h, const float* __restrict__ attn_t,
        float* __restrict__ eh, float* __restrict__ et) {
    __shared__ float ahs[DIM], ats[DIM];
    const int t = threadIdx.x;
    if (t < DIM) { ahs[t] = attn_h[t]; ats[t] = attn_t[t]; }
    __syncthreads();
    const int idx  = blockIdx.x * 256 + t;
    const int n    = idx >> 3;
    const int head = idx & 7;
    const u16* fp = &feat0[(size_t)n * DIM + head * 16];
    float sh = 0.f, st = 0.f;
#pragma unroll
    for (int i = 0; i < 4; ++i) {
        const ushort4 f4 = ((const ushort4*)fp)[i];
        const int c = head * 16 + i * 4;
        sh += bf2f(f4.x) * ahs[c+0] + bf2f(f4.y) * ahs[c+1]
            + bf2f(f4.z) * ahs[c+2] + bf2f(f4.w) * ahs[c+3];
        st += bf2f(f4.x) * ats[c+0] + bf2f(f4.y) * ats[c+1]
            + bf2f(f4.z) * ats[c+2] + bf2f(f4.w) * ats[c+3];
    }
    eh[idx] = sh;
    et[idx] = st;
}

// ---------------- er[r][head] = ((rel_feat @ W_rel) * attn_r).sum ----------
__global__ __launch_bounds__(128) void rel_k(const float* __restrict__ rel_feat,
        const float* __restrict__ W,
        const float* __restrict__ attn_r, float* __restrict__ er) {
    __shared__ float rf[DIM];
    __shared__ float pr[DIM];
    const int r = blockIdx.x, t = threadIdx.x;
    rf[t] = rel_feat[r * DIM + t];
    __syncthreads();
    float acc = 0.f;
    for (int d = 0; d < DIM; ++d) acc += rf[d] * W[d * DIM + t];
    pr[t] = acc * attn_r[t];
    __syncthreads();
    if (t < NHEAD) {
        float s = 0.f;
        for (int i = 0; i < 16; ++i) s += pr[t * 16 + i];
        er[r * NHEAD + t] = s;
    }
}

// ---------------- CSR build: histogram, 3-phase scan, scatter ---------------
__global__ void count_k(const int* __restrict__ dst, int* __restrict__ counts) {
    int e = blockIdx.x * blockDim.x + threadIdx.x;
    if (e < N_EDGES) atomicAdd(&counts[dst[e]], 1);
}

__global__ __launch_bounds__(256) void scan1_k(const int* __restrict__ counts,
        int* __restrict__ offsets, int* __restrict__ blk_sums, int n) {
    __shared__ int wsum[4];
    const int t = threadIdx.x, lane = t & 63, wid = t >> 6;
    const int base = blockIdx.x * SCHUNK + t * 4;
    int v0 = 0, v1 = 0, v2 = 0, v3 = 0;
    if (base + 3 < n) {
        const int4 c4 = *(const int4*)&counts[base];
        v0 = c4.x; v1 = c4.y; v2 = c4.z; v3 = c4.w;
    } else {
        if (base + 0 < n) v0 = counts[base + 0];
        if (base + 1 < n) v1 = counts[base + 1];
        if (base + 2 < n) v2 = counts[base + 2];
        if (base + 3 < n) v3 = counts[base + 3];
    }
    const int s4 = v0 + v1 + v2 + v3;
    int incl = s4;
#pragma unroll
    for (int off = 1; off < 64; off <<= 1) {
        const int tt = __shfl_up(incl, off, 64);
        if (lane >= off) incl += tt;
    }
    if (lane == 63) wsum[wid] = incl;
    __syncthreads();
    int wbase = 0;
#pragma unroll
    for (int w = 0; w < 4; ++w) if (w < wid) wbase += wsum[w];
    const int excl = wbase + incl - s4;
    if (base + 0 < n) offsets[base + 0] = excl;
    if (base + 1 < n) offsets[base + 1] = excl + v0;
    if (base + 2 < n) offsets[base + 2] = excl + v0 + v1;
    if (base + 3 < n) offsets[base + 3] = excl + v0 + v1 + v2;
    if (t == 255) blk_sums[blockIdx.x] = wbase + incl;
}

__global__ __launch_bounds__(128) void scan2_k(const int* __restrict__ blk_sums,
        int* __restrict__ blk_off, int* __restrict__ offsets, int nblk, int n) {
    const int t = threadIdx.x;
    const int v = (t < nblk) ? blk_sums[t] : 0;
    int incl = v;
#pragma unroll
    for (int off = 1; off < 64; off <<= 1) {
        const int tt = __shfl_up(incl, off, 64);
        if ((t & 63) >= off) incl += tt;
    }
    __shared__ int w0sum;
    if (t == 63) w0sum = incl;
    __syncthreads();
    int x = incl - v;
    if (t >= 64) x += w0sum;
    if (t < nblk) blk_off[t] = x;
    if (t == nblk - 1) offsets[n] = x + v;
}

__global__ __launch_bounds__(256) void scan3_k(int* __restrict__ offsets,
        int* __restrict__ cursor, const int* __restrict__ blk_off, int n) {
    const int add  = blk_off[blockIdx.x];
    const int base = blockIdx.x * SCHUNK + threadIdx.x * 4;
#pragma unroll
    for (int j = 0; j < 4; ++j) {
        const int i = base + j;
        if (i < n) {
            const int o = offsets[i] + add;
            offsets[i] = o;
            cursor[i]  = o;
        }
    }
}

// windowed scatter: block b handles dst-window (b&7) over edge chunk (b>>3).
__global__ __launch_bounds__(256) void scatter_k(const int* __restrict__ src,
        const int* __restrict__ dst, const int* __restrict__ etype,
        int* __restrict__ cursor, u32* __restrict__ csr_se) {
    const int b  = blockIdx.x;          // 2048 blocks
    const int w  = b & (NWIN - 1);
    const int r  = b >> 3;
    const int lo = w * WNODES, hi = lo + WNODES;
    const int base = r * ECHUNK;
    for (int i = threadIdx.x; i < ECHUNK; i += 256) {
        const int e = base + i;
        const int d = dst[e];
        if (d >= lo && d < hi) {
            const int s   = src[e];
            const int rel = etype[e];
            const int pos = atomicAdd(&cursor[d], 1);
            if (pos >= 0 && pos < N_EDGES)
                csr_se[pos] = (u32)s | ((u32)rel << 17);
        }
    }
}

// --------- edge softmax: compute scores on the fly, write exp (bf16) --------
// 4 nodes per 256-thread block (1 wave/node); lane -> (slot=lane/8, head=lane%8)
__global__ __launch_bounds__(256) void softmax_k(const int* __restrict__ offsets,
        const u32* __restrict__ csr_se,
        const float* __restrict__ eh, const float* __restrict__ et,
        const float* __restrict__ er,
        u16* __restrict__ csr_ab, float* __restrict__ inv_buf) {
    const int n = blockIdx.x * 4 + (threadIdx.x >> 6);
    const int beg = offsets[n], end = offsets[n + 1];
    const int lane = threadIdx.x & 63;
    const int k  = lane & 7;
    const int eo = lane >> 3;
    const float etk = et[n * NHEAD + k];
    float m = -1e30f;
    for (int e = beg + eo; e < end; e += 8) {
        const u32 se = csr_se[e];
        const int s = se & 0x1FFFF;
        const int r = se >> 17;
        float sc = eh[s * NHEAD + k] + etk + er[r * NHEAD + k];
        sc = sc > 0.f ? sc : SLOPE * sc;
        m = fmaxf(m, sc);
    }
    m = fmaxf(m, __shfl_xor(m, 8, 64));
    m = fmaxf(m, __shfl_xor(m, 16, 64));
    m = fmaxf(m, __shfl_xor(m, 32, 64));
    float ssum = 0.f;
    for (int e = beg + eo; e < end; e += 8) {
        const u32 se = csr_se[e];
        const int s = se & 0x1FFFF;
        const int r = se >> 17;
        float sc = eh[s * NHEAD + k] + etk + er[r * NHEAD + k];
        sc = sc > 0.f ? sc : SLOPE * sc;
        const float ex = expf(sc - m);
        csr_ab[(size_t)e * NHEAD + k] = f2bf(ex);
        ssum += ex;
    }
    ssum += __shfl_xor(ssum, 8, 64);
    ssum += __shfl_xor(ssum, 16, 64);
    ssum += __shfl_xor(ssum, 32, 64);
    const float inv = 1.f / fmaxf(ssum, 1e-20f);
    if (lane < 8) inv_buf[n * NHEAD + lane] = inv;
}

// ---------------- one PPR diffusion hop (bf16 f, bf16 a, deferred norm) ----
// v1 (best measured): wave per node; 16 lanes x 16B cover one 256B row;
// 4 edges in flight per 16-edge tile; no forced launch bounds.
__global__ __launch_bounds__(256) void hop_k(const u16* __restrict__ f_in,
        u16* __restrict__ f_out, const u16* __restrict__ feat0,
        const int* __restrict__ offsets, const u32* __restrict__ csr_se,
        const u16* __restrict__ csr_ab, const float* __restrict__ inv_buf) {
    const int n    = blockIdx.x * 4 + (threadIdx.x >> 6);
    const int lane = threadIdx.x & 63;
    const int li   = lane & 15;     // position within a 256B row (16B each)
    const int grp  = lane >> 4;     // which of 4 concurrent edges
    const int hsel = li >> 1;       // head owning this lane's 8 dims
    const int beg = offsets[n], end = offsets[n + 1];
    const int deg = end - beg;

    float acc[8];
#pragma unroll
    for (int j = 0; j < 8; ++j) acc[j] = 0.f;

    const int nfull = deg >> 4;
    int e0 = beg;
    for (int i = 0; i < nfull; ++i, e0 += 16) {
        const u32 se16 = csr_se[e0 + li];          // 16 edges' packed src
#pragma unroll
        for (int u = 0; u < 4; ++u) {
            const int eu = e0 + u * 4 + grp;
            const u32 se = __shfl(se16, u * 4 + grp, 16);
            const int s  = (int)(se & 0x1FFFF);
            const float a = bf2f(csr_ab[(size_t)eu * NHEAD + hsel]);
            const bf16x8 row = *(const bf16x8*)&f_in[(size_t)s * DIM + li * 8];
#pragma unroll
            for (int j = 0; j < 8; ++j)
                acc[j] += a * bf2f((u16)row[j]);
        }
    }
    for (int e = e0 + grp; e < end; e += 4) {
        const u32 se = csr_se[e];
        const int s  = (int)(se & 0x1FFFF);
        const float a = bf2f(csr_ab[(size_t)e * NHEAD + hsel]);
        const bf16x8 row = *(const bf16x8*)&f_in[(size_t)s * DIM + li * 8];
#pragma unroll
        for (int j = 0; j < 8; ++j)
            acc[j] += a * bf2f((u16)row[j]);
    }
#pragma unroll
    for (int j = 0; j < 8; ++j) {
        acc[j] += __shfl_xor(acc[j], 16, 64);
        acc[j] += __shfl_xor(acc[j], 32, 64);
    }
    if (lane < 16) {
        const float iv = inv_buf[n * NHEAD + hsel];
        const bf16x8 p = *(const bf16x8*)&feat0[(size_t)n * DIM + li * 8];
        bf16x8 o;
#pragma unroll
        for (int j = 0; j < 8; ++j)
            o[j] = (short)f2bf((1.f - ALPHA) * acc[j] * iv + ALPHA * bf2f((u16)p[j]));
        *(bf16x8*)&f_out[(size_t)n * DIM + li * 8] = o;
    }
}

// ---------------- FFN sublayer via MFMA bf16 + residuals, fp32 out ---------
// 16 nodes/block -> LDS ~21KB -> 7 blocks/CU (latency hiding via occupancy).
#define YP 136
#define ZP 520
__global__ __launch_bounds__(256) void ffn_k(const u16* __restrict__ f,
        const float* __restrict__ h,
        const float* __restrict__ g2, const float* __restrict__ b2ln,
        const u16* __restrict__ W1s,  // [DFF][DIM] bf16, k-contig
        const float* __restrict__ b1,
        const u16* __restrict__ W2s,  // [DIM][DFF] bf16, k-contig
        const float* __restrict__ b2,
        float* __restrict__ out) {
    __shared__ u16 ysb[FNODES * YP];   // 4.3 KB
    __shared__ u16 zsb[FNODES * ZP];   // 16.6 KB

    const int t    = threadIdx.x;
    const int n0b  = blockIdx.x * FNODES;
    const int wv   = t >> 6;
    const int lane = t & 63;

    // Phase A: LN of 16 nodes; thread t -> node t>>4, dims (t&15)*8..+8;
    // reduce across the 16 lanes owning one node via shuffles.
    {
        const int node = t >> 4;
        const int cp   = (t & 15) * 8;
        const int gbase = (n0b + node) * DIM + cp;
        const ushort4 fu0 = *(const ushort4*)&f[gbase];
        const ushort4 fu1 = *(const ushort4*)&f[gbase + 4];
        const float4  hv0 = *(const float4*)&h[gbase];
        const float4  hv1 = *(const float4*)&h[gbase + 4];
        float rv[8];
        rv[0] = bf2f(fu0.x) + hv0.x; rv[1] = bf2f(fu0.y) + hv0.y;
        rv[2] = bf2f(fu0.z) + hv0.z; rv[3] = bf2f(fu0.w) + hv0.w;
        rv[4] = bf2f(fu1.x) + hv1.x; rv[5] = bf2f(fu1.y) + hv1.y;
        rv[6] = bf2f(fu1.z) + hv1.z; rv[7] = bf2f(fu1.w) + hv1.w;
        float s = 0.f, q = 0.f;
#pragma unroll
        for (int i = 0; i < 8; ++i) { s += rv[i]; q += rv[i] * rv[i]; }
        s += __shfl_xor(s, 1, 64); q += __shfl_xor(q, 1, 64);
        s += __shfl_xor(s, 2, 64); q += __shfl_xor(q, 2, 64);
        s += __shfl_xor(s, 4, 64); q += __shfl_xor(q, 4, 64);
        s += __shfl_xor(s, 8, 64); q += __shfl_xor(q, 8, 64);
        const float mu  = s * (1.0f / 128.0f);
        const float var = q * (1.0f / 128.0f) - mu * mu;
        const float rs  = rsqrtf(fmaxf(var, 0.f) + LN_EPS);
        ushort4 yo0, yo1;
        yo0.x = f2bf((rv[0] - mu) * rs * g2[cp+0] + b2ln[cp+0]);
        yo0.y = f2bf((rv[1] - mu) * rs * g2[cp+1] + b2ln[cp+1]);
        yo0.z = f2bf((rv[2] - mu) * rs * g2[cp+2] + b2ln[cp+2]);
        yo0.w = f2bf((rv[3] - mu) * rs * g2[cp+3] + b2ln[cp+3]);
        yo1.x = f2bf((rv[4] - mu) * rs * g2[cp+4] + b2ln[cp+4]);
        yo1.y = f2bf((rv[5] - mu) * rs * g2[cp+5] + b2ln[cp+5]);
        yo1.z = f2bf((rv[6] - mu) * rs * g2[cp+6] + b2ln[cp+6]);
        yo1.w = f2bf((rv[7] - mu) * rs * g2[cp+7] + b2ln[cp+7]);
        *(ushort4*)&ysb[node * YP + cp]     = yo0;
        *(ushort4*)&ysb[node * YP + cp + 4] = yo1;
    }
    __syncthreads();

    const int lm = lane & 15;
    const int q4 = lane >> 4;

    // Phase B: z = relu(y @ W1); wave wv -> z-cols [wv*128, wv*128+128)
    {
        bf16x8 afr[4];
#pragma unroll
        for (int kt = 0; kt < 4; ++kt)
            afr[kt] = *(const bf16x8*)&ysb[lm * YP + kt * 32 + q4 * 8];

        const int cw = wv * 128;
#pragma unroll
        for (int nt = 0; nt < 8; ++nt) {
            const int n0 = cw + nt * 16;
            f32x4 acc0 = {0.f, 0.f, 0.f, 0.f};
#pragma unroll
            for (int kt = 0; kt < 4; ++kt) {
                const bf16x8 bfr = *(const bf16x8*)&W1s[(n0 + lm) * DIM + kt * 32 + q4 * 8];
                acc0 = __builtin_amdgcn_mfma_f32_16x16x32_bf16(afr[kt], bfr, acc0, 0, 0, 0);
            }
            const float bias = b1[n0 + lm];
#pragma unroll
            for (int r = 0; r < 4; ++r)
                zsb[(q4 * 4 + r) * ZP + n0 + lm] = f2bf(fmaxf(acc0[r] + bias, 0.f));
        }
    }
    __syncthreads();

    // Phase C: out = z @ W2 (+bias +residuals); wave wv -> out-cols [wv*32,+32)
    f32x4 acc[2];
    acc[0] = (f32x4){0.f, 0.f, 0.f, 0.f};
    acc[1] = (f32x4){0.f, 0.f, 0.f, 0.f};
    const int c0 = wv * 32;
#pragma unroll
    for (int kt = 0; kt < 16; ++kt) {
        const bf16x8 a0  = *(const bf16x8*)&zsb[lm * ZP + kt * 32 + q4 * 8];
        const bf16x8 b0  = *(const bf16x8*)&W2s[(c0 + lm) * DFF + kt * 32 + q4 * 8];
        const bf16x8 b1f = *(const bf16x8*)&W2s[(c0 + 16 + lm) * DFF + kt * 32 + q4 * 8];
        acc[0] = __builtin_amdgcn_mfma_f32_16x16x32_bf16(a0, b0,  acc[0], 0, 0, 0);
        acc[1] = __builtin_amdgcn_mfma_f32_16x16x32_bf16(a0, b1f, acc[1], 0, 0, 0);
    }

#pragma unroll
    for (int ntile = 0; ntile < 2; ++ntile) {
        const int col = c0 + ntile * 16 + lm;
        const float bias = b2[col];
#pragma unroll
        for (int r = 0; r < 4; ++r) {
            const int row  = q4 * 4 + r;
            const int gidx = (n0b + row) * DIM + col;
            out[gidx] = acc[ntile][r] + bias + bf2f(f[gidx]) + h[gidx];
        }
    }
}

// ---------------------------------------------------------------------------
extern "C" void kernel_launch(void* const* d_in, const int* in_sizes, int n_in,
                              void* d_out, int out_size, void* d_ws, size_t ws_size,
                              hipStream_t stream) {
    const float* ent_feat = (const float*)d_in[0];
    const float* rel_feat = (const float*)d_in[1];
    const int*   src      = (const int*)d_in[2];
    const int*   dst      = (const int*)d_in[3];
    const int*   e_type   = (const int*)d_in[4];
    const float* ln1_g    = (const float*)d_in[5];
    const float* ln1_b    = (const float*)d_in[6];
    const float* W_ent    = (const float*)d_in[7];
    const float* W_rel    = (const float*)d_in[8];
    const float* attn_h   = (const float*)d_in[9];
    const float* attn_t   = (const float*)d_in[10];
    const float* attn_r   = (const float*)d_in[11];
    const float* ln2_g    = (const float*)d_in[12];
    const float* ln2_b    = (const float*)d_in[13];
    const float* W1       = (const float*)d_in[14];
    const float* b1       = (const float*)d_in[15];
    const float* W2       = (const float*)d_in[16];
    const float* b2       = (const float*)d_in[17];
    float* out = (float*)d_out;

    char* ws = (char*)d_ws;
    size_t used = 0;
    auto alloc = [&](size_t bytes) -> char* {
        char* p = ws + used;
        used += (bytes + 255) & ~(size_t)255;
        return p;
    };
    float* h       = (float*)alloc((size_t)N_NODES * DIM * 4);   // 51.2 MB
    u16*   feat0   = (u16*)  alloc((size_t)N_NODES * DIM * 2);   // 25.6 MB
    u16*   fA      = (u16*)  alloc((size_t)N_NODES * DIM * 2);   // 25.6 MB
    u16*   fB      = (u16*)  alloc((size_t)N_NODES * DIM * 2);   // 25.6 MB
    u16*   csr_ab  = (u16*)  alloc((size_t)N_EDGES * NHEAD * 2); // 25.6 MB
    float* eh      = (float*)alloc((size_t)N_NODES * NHEAD * 4); // 3.2 MB
    float* et      = (float*)alloc((size_t)N_NODES * NHEAD * 4); // 3.2 MB
    float* inv_buf = (float*)alloc((size_t)N_NODES * NHEAD * 4); // 3.2 MB
    u32*   csr_se  = (u32*)  alloc((size_t)N_EDGES * 4);         // 6.4 MB
    int*   counts  = (int*)  alloc((size_t)N_NODES * 4);
    int*   offsets = (int*)  alloc((size_t)(N_NODES + 1) * 4);
    int*   cursor  = (int*)  alloc((size_t)N_NODES * 4);
    float* er      = (float*)alloc((size_t)N_REL * NHEAD * 4);
    u16*   W1s     = (u16*)  alloc((size_t)DIM * DFF * 2);
    u16*   W2s     = (u16*)  alloc((size_t)DFF * DIM * 2);
    u16*   Wes     = (u16*)  alloc((size_t)DIM * DIM * 2);
    int*   blk_sums= (int*)  alloc((size_t)NSCANBLK * 4);
    int*   blk_off = (int*)  alloc((size_t)NSCANBLK * 4);

    if (used > ws_size) return;   // diagnostic: absmax == max|ref|

    swz1_k<<<DIM * DFF / 256, 256, 0, stream>>>(W1, W1s);
    swz2_k<<<DFF * DIM / 256, 256, 0, stream>>>(W2, W2s);
    swze_k<<<DIM * DIM / 256, 256, 0, stream>>>(W_ent, Wes);

    ln1_k<<<N_NODES, 128, 0, stream>>>(ent_feat, ln1_g, ln1_b, h);
    proj_k<<<N_NODES / 32, 256, 0, stream>>>(h, Wes, feat0);
    eh_k<<<N_NODES * NHEAD / 256, 256, 0, stream>>>(feat0, attn_h, attn_t, eh, et);
    rel_k<<<N_REL, 128, 0, stream>>>(rel_feat, W_rel, attn_r, er);

    zero_k<<<(N_NODES + 255) / 256, 256, 0, stream>>>(counts, N_NODES);
    count_k<<<(N_EDGES + 255) / 256, 256, 0, stream>>>(dst, counts);
    scan1_k<<<NSCANBLK, 256, 0, stream>>>(counts, offsets, blk_sums, N_NODES);
    scan2_k<<<1, 128, 0, stream>>>(blk_sums, blk_off, offsets, NSCANBLK, N_NODES);
    scan3_k<<<NSCANBLK, 256, 0, stream>>>(offsets, cursor, blk_off, N_NODES);
    scatter_k<<<NECHUNK * NWIN, 256, 0, stream>>>(src, dst, e_type,
                                                  cursor, csr_se);
    softmax_k<<<N_NODES / 4, 256, 0, stream>>>(offsets, csr_se, eh, et, er,
                                               csr_ab, inv_buf);

    // 5 PPR hops: feat0 -> fA -> fB -> fA -> fB -> fA
    hop_k<<<N_NODES / 4, 256, 0, stream>>>(feat0, fA, feat0, offsets, csr_se, csr_ab, inv_buf);
    hop_k<<<N_NODES / 4, 256, 0, stream>>>(fA, fB, feat0, offsets, csr_se, csr_ab, inv_buf);
    hop_k<<<N_NODES / 4, 256, 0, stream>>>(fB, fA, feat0, offsets, csr_se, csr_ab, inv_buf);
    hop_k<<<N_NODES / 4, 256, 0, stream>>>(fA, fB, feat0, offsets, csr_se, csr_ab, inv_buf);
    hop_k<<<N_NODES / 4, 256, 0, stream>>>(fB, fA, feat0, offsets, csr_se, csr_ab, inv_buf);

    // FFN + residuals (MFMA)
    ffn_k<<<N_NODES / FNODES, 256, 0, stream>>>(fA, h, ln2_g, ln2_b, W1s, b1, W2s, b2,
                                                out);
}

// Round 6
// 905.306 us; speedup vs baseline: 1.1674x; 1.0712x over previous
//
#include <hip/hip_runtime.h>
#include <hip/hip_bf16.h>
#include <math.h>

#define N_NODES 100000
#define N_EDGES 1600000
#define N_REL   500
#define DIM     128
#define NHEAD   8
#define DFF     512
#define ALPHA   0.15f
#define SLOPE   0.2f
#define LN_EPS  1e-5f

#define SCHUNK   1024
#define NSCANBLK ((N_NODES + SCHUNK - 1) / SCHUNK)   // 98

// windowed scatter: 8 windows of 12500 nodes; 256 edge chunks of 6250
#define NWIN    8
#define WNODES  12500
#define NECHUNK 256
#define ECHUNK  (N_EDGES / NECHUNK)   // 6250

typedef unsigned short u16;
typedef unsigned int   u32;

typedef __attribute__((ext_vector_type(8))) short  bf16x8;   // MFMA A/B frag
typedef __attribute__((ext_vector_type(4))) float  f32x4;    // MFMA C/D frag

__device__ __forceinline__ float bf2f(u16 u) {
    return __uint_as_float(((u32)u) << 16);
}
__device__ __forceinline__ u16 f2bf(float f) {
    __hip_bfloat16 b = __float2bfloat16(f);
    return *reinterpret_cast<u16*>(&b);
}

// ---------------- zero an int buffer (graph-capture-safe memset) ------------
__global__ void zero_k(int* __restrict__ p, int n) {
    int i = blockIdx.x * blockDim.x + threadIdx.x;
    if (i < n) p[i] = 0;
}

// ------ weight pre-swizzles to bf16, k-contiguous [n][k] --------------------
__global__ void swz1_k(const float* __restrict__ W1, u16* __restrict__ W1s) {
    const int i = blockIdx.x * 256 + threadIdx.x;       // 65536
    const int k = i >> 9, n = i & 511;
    W1s[n * DIM + k] = f2bf(W1[i]);
}
__global__ void swz2_k(const float* __restrict__ W2, u16* __restrict__ W2s) {
    const int i = blockIdx.x * 256 + threadIdx.x;       // 65536
    const int k = i >> 7, n = i & 127;
    W2s[n * DFF + k] = f2bf(W2[i]);
}
__global__ void swze_k(const float* __restrict__ W, u16* __restrict__ Ws) {
    const int i = blockIdx.x * 256 + threadIdx.x;       // 16384
    const int k = i >> 7, n = i & 127;
    Ws[n * DIM + k] = f2bf(W[i]);
}

// ---------------- LayerNorm 1 : h = LN(ent_feat)  (fp32 in/out) -------------
__global__ __launch_bounds__(128) void ln1_k(const float* __restrict__ x,
        const float* __restrict__ g, const float* __restrict__ b,
        float* __restrict__ h) {
    const int n = blockIdx.x, t = threadIdx.x;
    const float v = x[n * DIM + t];
    float s = v, q = v * v;
#pragma unroll
    for (int off = 32; off > 0; off >>= 1) {
        s += __shfl_xor(s, off, 64);
        q += __shfl_xor(q, off, 64);
    }
    __shared__ float ss[2], qq[2];
    if ((t & 63) == 0) { ss[t >> 6] = s; qq[t >> 6] = q; }
    __syncthreads();
    s = ss[0] + ss[1]; q = qq[0] + qq[1];
    const float mu  = s * (1.0f / 128.0f);
    const float var = q * (1.0f / 128.0f) - mu * mu;
    const float rs  = rsqrtf(fmaxf(var, 0.f) + LN_EPS);
    h[n * DIM + t] = (v - mu) * rs * g[t] + b[t];
}

// --------- feat0 = h @ W_ent via MFMA bf16 (32 nodes/block, 4 waves) --------
#define HP 136   // hsb row pitch (u16), 136 = 8*17 (keeps 16B frag alignment)
__global__ __launch_bounds__(256) void proj_k(const float* __restrict__ h,
        const u16* __restrict__ Wes,  // [DIM n][DIM k] bf16, k-contig
        u16* __restrict__ feat0) {
    __shared__ u16 hsb[32 * HP];
    const int t   = threadIdx.x;
    const int n0b = blockIdx.x * 32;

    // stage h (fp32 -> bf16) into LDS: thread t -> row t>>3, 16 cols
    {
        const int sr = t >> 3;
        const int sc = (t & 7) * 16;
        const float* hrow = &h[(size_t)(n0b + sr) * DIM + sc];
        u16* drow = &hsb[sr * HP + sc];
#pragma unroll
        for (int i = 0; i < 4; ++i) {
            const float4 hv = ((const float4*)hrow)[i];
            ushort4 o;
            o.x = f2bf(hv.x); o.y = f2bf(hv.y); o.z = f2bf(hv.z); o.w = f2bf(hv.w);
            ((ushort4*)drow)[i] = o;
        }
    }
    __syncthreads();

    const int wv   = t >> 6;
    const int lane = t & 63;
    const int lm   = lane & 15;
    const int q4   = lane >> 4;
    const int mrow = (wv & 1) * 16;        // rows [mrow, mrow+16)
    const int chalf = (wv >> 1) * 64;      // cols [chalf, chalf+64)

    bf16x8 afr[4];
#pragma unroll
    for (int kt = 0; kt < 4; ++kt)
        afr[kt] = *(const bf16x8*)&hsb[(mrow + lm) * HP + kt * 32 + q4 * 8];

#pragma unroll
    for (int nt = 0; nt < 4; ++nt) {
        const int c0 = chalf + nt * 16;
        f32x4 acc = {0.f, 0.f, 0.f, 0.f};
#pragma unroll
        for (int kt = 0; kt < 4; ++kt) {
            const bf16x8 bfr = *(const bf16x8*)&Wes[(c0 + lm) * DIM + kt * 32 + q4 * 8];
            acc = __builtin_amdgcn_mfma_f32_16x16x32_bf16(afr[kt], bfr, acc, 0, 0, 0);
        }
#pragma unroll
        for (int r = 0; r < 4; ++r)
            feat0[(size_t)(n0b + mrow + q4 * 4 + r) * DIM + c0 + lm] = f2bf(acc[r]);
    }
}

// --------- eh/et: per-head attn dots from feat0 -----------------------------
__global__ __launch_bounds__(256) void eh_k(const u16* __restrict__ feat0,
        const float* __restrict__ attn_h, const float* __restrict__ attn_t,
        float* __restrict__ eh, float* __restrict__ et) {
    __shared__ float ahs[DIM], ats[DIM];
    const int t = threadIdx.x;
    if (t < DIM) { ahs[t] = attn_h[t]; ats[t] = attn_t[t]; }
    __syncthreads();
    const int idx  = blockIdx.x * 256 + t;
    const int n    = idx >> 3;
    const int head = idx & 7;
    const u16* fp = &feat0[(size_t)n * DIM + head * 16];
    float sh = 0.f, st = 0.f;
#pragma unroll
    for (int i = 0; i < 4; ++i) {
        const ushort4 f4 = ((const ushort4*)fp)[i];
        const int c = head * 16 + i * 4;
        sh += bf2f(f4.x) * ahs[c+0] + bf2f(f4.y) * ahs[c+1]
            + bf2f(f4.z) * ahs[c+2] + bf2f(f4.w) * ahs[c+3];
        st += bf2f(f4.x) * ats[c+0] + bf2f(f4.y) * ats[c+1]
            + bf2f(f4.z) * ats[c+2] + bf2f(f4.w) * ats[c+3];
    }
    eh[idx] = sh;
    et[idx] = st;
}

// ---------------- er[r][head] = ((rel_feat @ W_rel) * attn_r).sum ----------
__global__ __launch_bounds__(128) void rel_k(const float* __restrict__ rel_feat,
        const float* __restrict__ W,
        const float* __restrict__ attn_r, float* __restrict__ er) {
    __shared__ float rf[DIM];
    __shared__ float pr[DIM];
    const int r = blockIdx.x, t = threadIdx.x;
    rf[t] = rel_feat[r * DIM + t];
    __syncthreads();
    float acc = 0.f;
    for (int d = 0; d < DIM; ++d) acc += rf[d] * W[d * DIM + t];
    pr[t] = acc * attn_r[t];
    __syncthreads();
    if (t < NHEAD) {
        float s = 0.f;
        for (int i = 0; i < 16; ++i) s += pr[t * 16 + i];
        er[r * NHEAD + t] = s;
    }
}

// ---------------- CSR build: histogram, 3-phase scan, scatter ---------------
__global__ void count_k(const int* __restrict__ dst, int* __restrict__ counts) {
    int e = blockIdx.x * blockDim.x + threadIdx.x;
    if (e < N_EDGES) atomicAdd(&counts[dst[e]], 1);
}

__global__ __launch_bounds__(256) void scan1_k(const int* __restrict__ counts,
        int* __restrict__ offsets, int* __restrict__ blk_sums, int n) {
    __shared__ int wsum[4];
    const int t = threadIdx.x, lane = t & 63, wid = t >> 6;
    const int base = blockIdx.x * SCHUNK + t * 4;
    int v0 = 0, v1 = 0, v2 = 0, v3 = 0;
    if (base + 3 < n) {
        const int4 c4 = *(const int4*)&counts[base];
        v0 = c4.x; v1 = c4.y; v2 = c4.z; v3 = c4.w;
    } else {
        if (base + 0 < n) v0 = counts[base + 0];
        if (base + 1 < n) v1 = counts[base + 1];
        if (base + 2 < n) v2 = counts[base + 2];
        if (base + 3 < n) v3 = counts[base + 3];
    }
    const int s4 = v0 + v1 + v2 + v3;
    int incl = s4;
#pragma unroll
    for (int off = 1; off < 64; off <<= 1) {
        const int tt = __shfl_up(incl, off, 64);
        if (lane >= off) incl += tt;
    }
    if (lane == 63) wsum[wid] = incl;
    __syncthreads();
    int wbase = 0;
#pragma unroll
    for (int w = 0; w < 4; ++w) if (w < wid) wbase += wsum[w];
    const int excl = wbase + incl - s4;
    if (base + 0 < n) offsets[base + 0] = excl;
    if (base + 1 < n) offsets[base + 1] = excl + v0;
    if (base + 2 < n) offsets[base + 2] = excl + v0 + v1;
    if (base + 3 < n) offsets[base + 3] = excl + v0 + v1 + v2;
    if (t == 255) blk_sums[blockIdx.x] = wbase + incl;
}

__global__ __launch_bounds__(128) void scan2_k(const int* __restrict__ blk_sums,
        int* __restrict__ blk_off, int* __restrict__ offsets, int nblk, int n) {
    const int t = threadIdx.x;
    const int v = (t < nblk) ? blk_sums[t] : 0;
    int incl = v;
#pragma unroll
    for (int off = 1; off < 64; off <<= 1) {
        const int tt = __shfl_up(incl, off, 64);
        if ((t & 63) >= off) incl += tt;
    }
    __shared__ int w0sum;
    if (t == 63) w0sum = incl;
    __syncthreads();
    int x = incl - v;
    if (t >= 64) x += w0sum;
    if (t < nblk) blk_off[t] = x;
    if (t == nblk - 1) offsets[n] = x + v;
}

__global__ __launch_bounds__(256) void scan3_k(int* __restrict__ offsets,
        int* __restrict__ cursor, const int* __restrict__ blk_off, int n) {
    const int add  = blk_off[blockIdx.x];
    const int base = blockIdx.x * SCHUNK + threadIdx.x * 4;
#pragma unroll
    for (int j = 0; j < 4; ++j) {
        const int i = base + j;
        if (i < n) {
            const int o = offsets[i] + add;
            offsets[i] = o;
            cursor[i]  = o;
        }
    }
}

// windowed scatter: block b handles dst-window (b&7) over edge chunk (b>>3).
__global__ __launch_bounds__(256) void scatter_k(const int* __restrict__ src,
        const int* __restrict__ dst, const int* __restrict__ etype,
        int* __restrict__ cursor, u32* __restrict__ csr_se) {
    const int b  = blockIdx.x;          // 2048 blocks
    const int w  = b & (NWIN - 1);
    const int r  = b >> 3;
    const int lo = w * WNODES, hi = lo + WNODES;
    const int base = r * ECHUNK;
    for (int i = threadIdx.x; i < ECHUNK; i += 256) {
        const int e = base + i;
        const int d = dst[e];
        if (d >= lo && d < hi) {
            const int s   = src[e];
            const int rel = etype[e];
            const int pos = atomicAdd(&cursor[d], 1);
            if (pos >= 0 && pos < N_EDGES)
                csr_se[pos] = (u32)s | ((u32)rel << 17);
        }
    }
}

// --------- edge softmax: compute scores on the fly, write exp (bf16) --------
// 4 nodes per 256-thread block (1 wave/node); lane -> (slot=lane/8, head=lane%8)
__global__ __launch_bounds__(256) void softmax_k(const int* __restrict__ offsets,
        const u32* __restrict__ csr_se,
        const float* __restrict__ eh, const float* __restrict__ et,
        const float* __restrict__ er,
        u16* __restrict__ csr_ab, float* __restrict__ inv_buf) {
    const int n = blockIdx.x * 4 + (threadIdx.x >> 6);
    const int beg = offsets[n], end = offsets[n + 1];
    const int lane = threadIdx.x & 63;
    const int k  = lane & 7;
    const int eo = lane >> 3;
    const float etk = et[n * NHEAD + k];
    float m = -1e30f;
    for (int e = beg + eo; e < end; e += 8) {
        const u32 se = csr_se[e];
        const int s = se & 0x1FFFF;
        const int r = se >> 17;
        float sc = eh[s * NHEAD + k] + etk + er[r * NHEAD + k];
        sc = sc > 0.f ? sc : SLOPE * sc;
        m = fmaxf(m, sc);
    }
    m = fmaxf(m, __shfl_xor(m, 8, 64));
    m = fmaxf(m, __shfl_xor(m, 16, 64));
    m = fmaxf(m, __shfl_xor(m, 32, 64));
    float ssum = 0.f;
    for (int e = beg + eo; e < end; e += 8) {
        const u32 se = csr_se[e];
        const int s = se & 0x1FFFF;
        const int r = se >> 17;
        float sc = eh[s * NHEAD + k] + etk + er[r * NHEAD + k];
        sc = sc > 0.f ? sc : SLOPE * sc;
        const float ex = expf(sc - m);
        csr_ab[(size_t)e * NHEAD + k] = f2bf(ex);
        ssum += ex;
    }
    ssum += __shfl_xor(ssum, 8, 64);
    ssum += __shfl_xor(ssum, 16, 64);
    ssum += __shfl_xor(ssum, 32, 64);
    const float inv = 1.f / fmaxf(ssum, 1e-20f);
    if (lane < 8) inv_buf[n * NHEAD + lane] = inv;
}

// ---------------- one PPR diffusion hop (bf16 f, bf16 a, deferred norm) ----
// v1 (best measured): wave per node; 16 lanes x 16B cover one 256B row;
// 4 edges in flight per 16-edge tile; no forced launch bounds.
__global__ __launch_bounds__(256) void hop_k(const u16* __restrict__ f_in,
        u16* __restrict__ f_out, const u16* __restrict__ feat0,
        const int* __restrict__ offsets, const u32* __restrict__ csr_se,
        const u16* __restrict__ csr_ab, const float* __restrict__ inv_buf) {
    const int n    = blockIdx.x * 4 + (threadIdx.x >> 6);
    const int lane = threadIdx.x & 63;
    const int li   = lane & 15;     // position within a 256B row (16B each)
    const int grp  = lane >> 4;     // which of 4 concurrent edges
    const int hsel = li >> 1;       // head owning this lane's 8 dims
    const int beg = offsets[n], end = offsets[n + 1];
    const int deg = end - beg;

    float acc[8];
#pragma unroll
    for (int j = 0; j < 8; ++j) acc[j] = 0.f;

    const int nfull = deg >> 4;
    int e0 = beg;
    for (int i = 0; i < nfull; ++i, e0 += 16) {
        const u32 se16 = csr_se[e0 + li];          // 16 edges' packed src
#pragma unroll
        for (int u = 0; u < 4; ++u) {
            const int eu = e0 + u * 4 + grp;
            const u32 se = __shfl(se16, u * 4 + grp, 16);
            const int s  = (int)(se & 0x1FFFF);
            const float a = bf2f(csr_ab[(size_t)eu * NHEAD + hsel]);
            const bf16x8 row = *(const bf16x8*)&f_in[(size_t)s * DIM + li * 8];
#pragma unroll
            for (int j = 0; j < 8; ++j)
                acc[j] += a * bf2f((u16)row[j]);
        }
    }
    for (int e = e0 + grp; e < end; e += 4) {
        const u32 se = csr_se[e];
        const int s  = (int)(se & 0x1FFFF);
        const float a = bf2f(csr_ab[(size_t)e * NHEAD + hsel]);
        const bf16x8 row = *(const bf16x8*)&f_in[(size_t)s * DIM + li * 8];
#pragma unroll
        for (int j = 0; j < 8; ++j)
            acc[j] += a * bf2f((u16)row[j]);
    }
#pragma unroll
    for (int j = 0; j < 8; ++j) {
        acc[j] += __shfl_xor(acc[j], 16, 64);
        acc[j] += __shfl_xor(acc[j], 32, 64);
    }
    if (lane < 16) {
        const float iv = inv_buf[n * NHEAD + hsel];
        const bf16x8 p = *(const bf16x8*)&feat0[(size_t)n * DIM + li * 8];
        bf16x8 o;
#pragma unroll
        for (int j = 0; j < 8; ++j)
            o[j] = (short)f2bf((1.f - ALPHA) * acc[j] * iv + ALPHA * bf2f((u16)p[j]));
        *(bf16x8*)&f_out[(size_t)n * DIM + li * 8] = o;
    }
}

// ---------------- FFN sublayer via MFMA bf16 + residuals, fp32 out ---------
// 32 nodes/block (keeps 2x weight amortization), 512 threads (8 waves) to
// double waves/SIMD (3->6) at the same 42KB LDS / 3 blocks/CU.
#define YP 136
#define ZP 520
__global__ __launch_bounds__(512, 6) void ffn_k(const u16* __restrict__ f,
        const float* __restrict__ h,
        const float* __restrict__ g2, const float* __restrict__ b2ln,
        const u16* __restrict__ W1s,  // [DFF][DIM] bf16, k-contig
        const float* __restrict__ b1,
        const u16* __restrict__ W2s,  // [DIM][DFF] bf16, k-contig
        const float* __restrict__ b2,
        float* __restrict__ out) {
    __shared__ u16 ysb[32 * YP];   // 8.7 KB
    __shared__ u16 zsb[32 * ZP];   // 33.3 KB

    const int t    = threadIdx.x;
    const int n0b  = blockIdx.x * 32;
    const int wv   = t >> 6;       // 0..7
    const int lane = t & 63;

    // Phase A: LN of 32 nodes; thread t -> node t>>4, dims (t&15)*8..+8;
    // reduce across the 16 lanes owning one node via shuffles.
    {
        const int node = t >> 4;
        const int cp   = (t & 15) * 8;
        const int gbase = (n0b + node) * DIM + cp;
        const ushort4 fu0 = *(const ushort4*)&f[gbase];
        const ushort4 fu1 = *(const ushort4*)&f[gbase + 4];
        const float4  hv0 = *(const float4*)&h[gbase];
        const float4  hv1 = *(const float4*)&h[gbase + 4];
        float rv[8];
        rv[0] = bf2f(fu0.x) + hv0.x; rv[1] = bf2f(fu0.y) + hv0.y;
        rv[2] = bf2f(fu0.z) + hv0.z; rv[3] = bf2f(fu0.w) + hv0.w;
        rv[4] = bf2f(fu1.x) + hv1.x; rv[5] = bf2f(fu1.y) + hv1.y;
        rv[6] = bf2f(fu1.z) + hv1.z; rv[7] = bf2f(fu1.w) + hv1.w;
        float s = 0.f, q = 0.f;
#pragma unroll
        for (int i = 0; i < 8; ++i) { s += rv[i]; q += rv[i] * rv[i]; }
        s += __shfl_xor(s, 1, 64); q += __shfl_xor(q, 1, 64);
        s += __shfl_xor(s, 2, 64); q += __shfl_xor(q, 2, 64);
        s += __shfl_xor(s, 4, 64); q += __shfl_xor(q, 4, 64);
        s += __shfl_xor(s, 8, 64); q += __shfl_xor(q, 8, 64);
        const float mu  = s * (1.0f / 128.0f);
        const float var = q * (1.0f / 128.0f) - mu * mu;
        const float rs  = rsqrtf(fmaxf(var, 0.f) + LN_EPS);
        ushort4 yo0, yo1;
        yo0.x = f2bf((rv[0] - mu) * rs * g2[cp+0] + b2ln[cp+0]);
        yo0.y = f2bf((rv[1] - mu) * rs * g2[cp+1] + b2ln[cp+1]);
        yo0.z = f2bf((rv[2] - mu) * rs * g2[cp+2] + b2ln[cp+2]);
        yo0.w = f2bf((rv[3] - mu) * rs * g2[cp+3] + b2ln[cp+3]);
        yo1.x = f2bf((rv[4] - mu) * rs * g2[cp+4] + b2ln[cp+4]);
        yo1.y = f2bf((rv[5] - mu) * rs * g2[cp+5] + b2ln[cp+5]);
        yo1.z = f2bf((rv[6] - mu) * rs * g2[cp+6] + b2ln[cp+6]);
        yo1.w = f2bf((rv[7] - mu) * rs * g2[cp+7] + b2ln[cp+7]);
        *(ushort4*)&ysb[node * YP + cp]     = yo0;
        *(ushort4*)&ysb[node * YP + cp + 4] = yo1;
    }
    __syncthreads();

    const int lm = lane & 15;
    const int q4 = lane >> 4;

    // Phase B: z = relu(y @ W1); wave wv -> z-cols [wv*64, wv*64+64)
    {
        bf16x8 afr[2][4];
#pragma unroll
        for (int mt = 0; mt < 2; ++mt)
#pragma unroll
            for (int kt = 0; kt < 4; ++kt)
                afr[mt][kt] = *(const bf16x8*)&ysb[(mt * 16 + lm) * YP + kt * 32 + q4 * 8];

        const int cw = wv * 64;
#pragma unroll
        for (int nt = 0; nt < 4; ++nt) {
            const int n0 = cw + nt * 16;
            f32x4 acc0 = {0.f, 0.f, 0.f, 0.f};
            f32x4 acc1 = {0.f, 0.f, 0.f, 0.f};
#pragma unroll
            for (int kt = 0; kt < 4; ++kt) {
                const bf16x8 bfr = *(const bf16x8*)&W1s[(n0 + lm) * DIM + kt * 32 + q4 * 8];
                acc0 = __builtin_amdgcn_mfma_f32_16x16x32_bf16(afr[0][kt], bfr, acc0, 0, 0, 0);
                acc1 = __builtin_amdgcn_mfma_f32_16x16x32_bf16(afr[1][kt], bfr, acc1, 0, 0, 0);
            }
            const float bias = b1[n0 + lm];
#pragma unroll
            for (int r = 0; r < 4; ++r) {
                zsb[(q4 * 4 + r) * ZP + n0 + lm]      = f2bf(fmaxf(acc0[r] + bias, 0.f));
                zsb[(16 + q4 * 4 + r) * ZP + n0 + lm] = f2bf(fmaxf(acc1[r] + bias, 0.f));
            }
        }
    }
    __syncthreads();

    // Phase C: out = z @ W2 (+bias +residuals); wave wv -> out-cols [wv*16,+16)
    f32x4 acc[2];
    acc[0] = (f32x4){0.f, 0.f, 0.f, 0.f};
    acc[1] = (f32x4){0.f, 0.f, 0.f, 0.f};
    const int c0 = wv * 16;
#pragma unroll
    for (int kt = 0; kt < 16; ++kt) {
        const bf16x8 a0 = *(const bf16x8*)&zsb[lm * ZP + kt * 32 + q4 * 8];
        const bf16x8 a1 = *(const bf16x8*)&zsb[(16 + lm) * ZP + kt * 32 + q4 * 8];
        const bf16x8 b0 = *(const bf16x8*)&W2s[(c0 + lm) * DFF + kt * 32 + q4 * 8];
        acc[0] = __builtin_amdgcn_mfma_f32_16x16x32_bf16(a0, b0, acc[0], 0, 0, 0);
        acc[1] = __builtin_amdgcn_mfma_f32_16x16x32_bf16(a1, b0, acc[1], 0, 0, 0);
    }

    {
        const int col = c0 + lm;
        const float bias = b2[col];
#pragma unroll
        for (int mt = 0; mt < 2; ++mt) {
#pragma unroll
            for (int r = 0; r < 4; ++r) {
                const int row  = mt * 16 + q4 * 4 + r;
                const int gidx = (n0b + row) * DIM + col;
                out[gidx] = acc[mt][r] + bias + bf2f(f[gidx]) + h[gidx];
            }
        }
    }
}

// ---------------------------------------------------------------------------
extern "C" void kernel_launch(void* const* d_in, const int* in_sizes, int n_in,
                              void* d_out, int out_size, void* d_ws, size_t ws_size,
                              hipStream_t stream) {
    const float* ent_feat = (const float*)d_in[0];
    const float* rel_feat = (const float*)d_in[1];
    const int*   src      = (const int*)d_in[2];
    const int*   dst      = (const int*)d_in[3];
    const int*   e_type   = (const int*)d_in[4];
    const float* ln1_g    = (const float*)d_in[5];
    const float* ln1_b    = (const float*)d_in[6];
    const float* W_ent    = (const float*)d_in[7];
    const float* W_rel    = (const float*)d_in[8];
    const float* attn_h   = (const float*)d_in[9];
    const float* attn_t   = (const float*)d_in[10];
    const float* attn_r   = (const float*)d_in[11];
    const float* ln2_g    = (const float*)d_in[12];
    const float* ln2_b    = (const float*)d_in[13];
    const float* W1       = (const float*)d_in[14];
    const float* b1       = (const float*)d_in[15];
    const float* W2       = (const float*)d_in[16];
    const float* b2       = (const float*)d_in[17];
    float* out = (float*)d_out;

    char* ws = (char*)d_ws;
    size_t used = 0;
    auto alloc = [&](size_t bytes) -> char* {
        char* p = ws + used;
        used += (bytes + 255) & ~(size_t)255;
        return p;
    };
    float* h       = (float*)alloc((size_t)N_NODES * DIM * 4);   // 51.2 MB
    u16*   feat0   = (u16*)  alloc((size_t)N_NODES * DIM * 2);   // 25.6 MB
    u16*   fA      = (u16*)  alloc((size_t)N_NODES * DIM * 2);   // 25.6 MB
    u16*   fB      = (u16*)  alloc((size_t)N_NODES * DIM * 2);   // 25.6 MB
    u16*   csr_ab  = (u16*)  alloc((size_t)N_EDGES * NHEAD * 2); // 25.6 MB
    float* eh      = (float*)alloc((size_t)N_NODES * NHEAD * 4); // 3.2 MB
    float* et      = (float*)alloc((size_t)N_NODES * NHEAD * 4); // 3.2 MB
    float* inv_buf = (float*)alloc((size_t)N_NODES * NHEAD * 4); // 3.2 MB
    u32*   csr_se  = (u32*)  alloc((size_t)N_EDGES * 4);         // 6.4 MB
    int*   counts  = (int*)  alloc((size_t)N_NODES * 4);
    int*   offsets = (int*)  alloc((size_t)(N_NODES + 1) * 4);
    int*   cursor  = (int*)  alloc((size_t)N_NODES * 4);
    float* er      = (float*)alloc((size_t)N_REL * NHEAD * 4);
    u16*   W1s     = (u16*)  alloc((size_t)DIM * DFF * 2);
    u16*   W2s     = (u16*)  alloc((size_t)DFF * DIM * 2);
    u16*   Wes     = (u16*)  alloc((size_t)DIM * DIM * 2);
    int*   blk_sums= (int*)  alloc((size_t)NSCANBLK * 4);
    int*   blk_off = (int*)  alloc((size_t)NSCANBLK * 4);

    if (used > ws_size) return;   // diagnostic: absmax == max|ref|

    swz1_k<<<DIM * DFF / 256, 256, 0, stream>>>(W1, W1s);
    swz2_k<<<DFF * DIM / 256, 256, 0, stream>>>(W2, W2s);
    swze_k<<<DIM * DIM / 256, 256, 0, stream>>>(W_ent, Wes);

    ln1_k<<<N_NODES, 128, 0, stream>>>(ent_feat, ln1_g, ln1_b, h);
    proj_k<<<N_NODES / 32, 256, 0, stream>>>(h, Wes, feat0);
    eh_k<<<N_NODES * NHEAD / 256, 256, 0, stream>>>(feat0, attn_h, attn_t, eh, et);
    rel_k<<<N_REL, 128, 0, stream>>>(rel_feat, W_rel, attn_r, er);

    zero_k<<<(N_NODES + 255) / 256, 256, 0, stream>>>(counts, N_NODES);
    count_k<<<(N_EDGES + 255) / 256, 256, 0, stream>>>(dst, counts);
    scan1_k<<<NSCANBLK, 256, 0, stream>>>(counts, offsets, blk_sums, N_NODES);
    scan2_k<<<1, 128, 0, stream>>>(blk_sums, blk_off, offsets, NSCANBLK, N_NODES);
    scan3_k<<<NSCANBLK, 256, 0, stream>>>(offsets, cursor, blk_off, N_NODES);
    scatter_k<<<NECHUNK * NWIN, 256, 0, stream>>>(src, dst, e_type,
                                                  cursor, csr_se);
    softmax_k<<<N_NODES / 4, 256, 0, stream>>>(offsets, csr_se, eh, et, er,
                                               csr_ab, inv_buf);

    // 5 PPR hops: feat0 -> fA -> fB -> fA -> fB -> fA
    hop_k<<<N_NODES / 4, 256, 0, stream>>>(feat0, fA, feat0, offsets, csr_se, csr_ab, inv_buf);
    hop_k<<<N_NODES / 4, 256, 0, stream>>>(fA, fB, feat0, offsets, csr_se, csr_ab, inv_buf);
    hop_k<<<N_NODES / 4, 256, 0, stream>>>(fB, fA, feat0, offsets, csr_se, csr_ab, inv_buf);
    hop_k<<<N_NODES / 4, 256, 0, stream>>>(fA, fB, feat0, offsets, csr_se, csr_ab, inv_buf);
    hop_k<<<N_NODES / 4, 256, 0, stream>>>(fB, fA, feat0, offsets, csr_se, csr_ab, inv_buf);

    // FFN + residuals (MFMA)
    ffn_k<<<N_NODES / 32, 512, 0, stream>>>(fA, h, ln2_g, ln2_b, W1s, b1, W2s, b2,
                                            out);
}

// Round 7
// 888.167 us; speedup vs baseline: 1.1899x; 1.0193x over previous
//
#include <hip/hip_runtime.h>
#include <hip/hip_bf16.h>
#include <math.h>

#define N_NODES 100000
#define N_EDGES 1600000
#define N_REL   500
#define DIM     128
#define NHEAD   8
#define DFF     512
#define ALPHA   0.15f
#define SLOPE   0.2f
#define LN_EPS  1e-5f

#define SCHUNK   1024
#define NSCANBLK ((N_NODES + SCHUNK - 1) / SCHUNK)   // 98

// windowed scatter: 8 windows of 12500 nodes; 256 edge chunks of 6250
#define NWIN    8
#define WNODES  12500
#define NECHUNK 256
#define ECHUNK  (N_EDGES / NECHUNK)   // 6250

typedef unsigned short u16;
typedef unsigned int   u32;

typedef __attribute__((ext_vector_type(8))) short  bf16x8;   // MFMA A/B frag
typedef __attribute__((ext_vector_type(4))) float  f32x4;    // MFMA C/D frag

__device__ __forceinline__ float bf2f(u16 u) {
    return __uint_as_float(((u32)u) << 16);
}
__device__ __forceinline__ u16 f2bf(float f) {
    __hip_bfloat16 b = __float2bfloat16(f);
    return *reinterpret_cast<u16*>(&b);
}

// paired bf16 extraction: 1 VALU + 1 FMA per element
__device__ __forceinline__ void fma_row(float* acc, float a, const bf16x8& r) {
    const u32* w = (const u32*)&r;
#pragma unroll
    for (int jj = 0; jj < 4; ++jj) {
        acc[2 * jj]     += a * __uint_as_float(w[jj] << 16);
        acc[2 * jj + 1] += a * __uint_as_float(w[jj] & 0xffff0000u);
    }
}

// ---------------- zero an int buffer (graph-capture-safe memset) ------------
__global__ void zero_k(int* __restrict__ p, int n) {
    int i = blockIdx.x * blockDim.x + threadIdx.x;
    if (i < n) p[i] = 0;
}

// ------ weight pre-swizzles to bf16, k-contiguous [n][k] --------------------
__global__ void swz1_k(const float* __restrict__ W1, u16* __restrict__ W1s) {
    const int i = blockIdx.x * 256 + threadIdx.x;       // 65536
    const int k = i >> 9, n = i & 511;
    W1s[n * DIM + k] = f2bf(W1[i]);
}
__global__ void swz2_k(const float* __restrict__ W2, u16* __restrict__ W2s) {
    const int i = blockIdx.x * 256 + threadIdx.x;       // 65536
    const int k = i >> 7, n = i & 127;
    W2s[n * DFF + k] = f2bf(W2[i]);
}
__global__ void swze_k(const float* __restrict__ W, u16* __restrict__ Ws) {
    const int i = blockIdx.x * 256 + threadIdx.x;       // 16384
    const int k = i >> 7, n = i & 127;
    Ws[n * DIM + k] = f2bf(W[i]);
}

// ---------------- LayerNorm 1 : h = LN(ent_feat)  (fp32 in/out) -------------
__global__ __launch_bounds__(128) void ln1_k(const float* __restrict__ x,
        const float* __restrict__ g, const float* __restrict__ b,
        float* __restrict__ h) {
    const int n = blockIdx.x, t = threadIdx.x;
    const float v = x[n * DIM + t];
    float s = v, q = v * v;
#pragma unroll
    for (int off = 32; off > 0; off >>= 1) {
        s += __shfl_xor(s, off, 64);
        q += __shfl_xor(q, off, 64);
    }
    __shared__ float ss[2], qq[2];
    if ((t & 63) == 0) { ss[t >> 6] = s; qq[t >> 6] = q; }
    __syncthreads();
    s = ss[0] + ss[1]; q = qq[0] + qq[1];
    const float mu  = s * (1.0f / 128.0f);
    const float var = q * (1.0f / 128.0f) - mu * mu;
    const float rs  = rsqrtf(fmaxf(var, 0.f) + LN_EPS);
    h[n * DIM + t] = (v - mu) * rs * g[t] + b[t];
}

// --------- feat0 = h @ W_ent via MFMA bf16 (32 nodes/block, 4 waves) --------
#define HP 136   // hsb row pitch (u16), 136 = 8*17 (keeps 16B frag alignment)
__global__ __launch_bounds__(256) void proj_k(const float* __restrict__ h,
        const u16* __restrict__ Wes,  // [DIM n][DIM k] bf16, k-contig
        u16* __restrict__ feat0) {
    __shared__ u16 hsb[32 * HP];
    const int t   = threadIdx.x;
    const int n0b = blockIdx.x * 32;

    // stage h (fp32 -> bf16) into LDS: thread t -> row t>>3, 16 cols
    {
        const int sr = t >> 3;
        const int sc = (t & 7) * 16;
        const float* hrow = &h[(size_t)(n0b + sr) * DIM + sc];
        u16* drow = &hsb[sr * HP + sc];
#pragma unroll
        for (int i = 0; i < 4; ++i) {
            const float4 hv = ((const float4*)hrow)[i];
            ushort4 o;
            o.x = f2bf(hv.x); o.y = f2bf(hv.y); o.z = f2bf(hv.z); o.w = f2bf(hv.w);
            ((ushort4*)drow)[i] = o;
        }
    }
    __syncthreads();

    const int wv   = t >> 6;
    const int lane = t & 63;
    const int lm   = lane & 15;
    const int q4   = lane >> 4;
    const int mrow = (wv & 1) * 16;        // rows [mrow, mrow+16)
    const int chalf = (wv >> 1) * 64;      // cols [chalf, chalf+64)

    bf16x8 afr[4];
#pragma unroll
    for (int kt = 0; kt < 4; ++kt)
        afr[kt] = *(const bf16x8*)&hsb[(mrow + lm) * HP + kt * 32 + q4 * 8];

#pragma unroll
    for (int nt = 0; nt < 4; ++nt) {
        const int c0 = chalf + nt * 16;
        f32x4 acc = {0.f, 0.f, 0.f, 0.f};
#pragma unroll
        for (int kt = 0; kt < 4; ++kt) {
            const bf16x8 bfr = *(const bf16x8*)&Wes[(c0 + lm) * DIM + kt * 32 + q4 * 8];
            acc = __builtin_amdgcn_mfma_f32_16x16x32_bf16(afr[kt], bfr, acc, 0, 0, 0);
        }
#pragma unroll
        for (int r = 0; r < 4; ++r)
            feat0[(size_t)(n0b + mrow + q4 * 4 + r) * DIM + c0 + lm] = f2bf(acc[r]);
    }
}

// --------- eh/et: per-head attn dots from feat0 -----------------------------
__global__ __launch_bounds__(256) void eh_k(const u16* __restrict__ feat0,
        const float* __restrict__ attn_h, const float* __restrict__ attn_t,
        float* __restrict__ eh, float* __restrict__ et) {
    __shared__ float ahs[DIM], ats[DIM];
    const int t = threadIdx.x;
    if (t < DIM) { ahs[t] = attn_h[t]; ats[t] = attn_t[t]; }
    __syncthreads();
    const int idx  = blockIdx.x * 256 + t;
    const int n    = idx >> 3;
    const int head = idx & 7;
    const u16* fp = &feat0[(size_t)n * DIM + head * 16];
    float sh = 0.f, st = 0.f;
#pragma unroll
    for (int i = 0; i < 4; ++i) {
        const ushort4 f4 = ((const ushort4*)fp)[i];
        const int c = head * 16 + i * 4;
        sh += bf2f(f4.x) * ahs[c+0] + bf2f(f4.y) * ahs[c+1]
            + bf2f(f4.z) * ahs[c+2] + bf2f(f4.w) * ahs[c+3];
        st += bf2f(f4.x) * ats[c+0] + bf2f(f4.y) * ats[c+1]
            + bf2f(f4.z) * ats[c+2] + bf2f(f4.w) * ats[c+3];
    }
    eh[idx] = sh;
    et[idx] = st;
}

// ---------------- er[r][head] = ((rel_feat @ W_rel) * attn_r).sum ----------
__global__ __launch_bounds__(128) void rel_k(const float* __restrict__ rel_feat,
        const float* __restrict__ W,
        const float* __restrict__ attn_r, float* __restrict__ er) {
    __shared__ float rf[DIM];
    __shared__ float pr[DIM];
    const int r = blockIdx.x, t = threadIdx.x;
    rf[t] = rel_feat[r * DIM + t];
    __syncthreads();
    float acc = 0.f;
    for (int d = 0; d < DIM; ++d) acc += rf[d] * W[d * DIM + t];
    pr[t] = acc * attn_r[t];
    __syncthreads();
    if (t < NHEAD) {
        float s = 0.f;
        for (int i = 0; i < 16; ++i) s += pr[t * 16 + i];
        er[r * NHEAD + t] = s;
    }
}

// ---------------- CSR build: histogram, 3-phase scan, scatter ---------------
__global__ void count_k(const int* __restrict__ dst, int* __restrict__ counts) {
    int e = blockIdx.x * blockDim.x + threadIdx.x;
    if (e < N_EDGES) atomicAdd(&counts[dst[e]], 1);
}

__global__ __launch_bounds__(256) void scan1_k(const int* __restrict__ counts,
        int* __restrict__ offsets, int* __restrict__ blk_sums, int n) {
    __shared__ int wsum[4];
    const int t = threadIdx.x, lane = t & 63, wid = t >> 6;
    const int base = blockIdx.x * SCHUNK + t * 4;
    int v0 = 0, v1 = 0, v2 = 0, v3 = 0;
    if (base + 3 < n) {
        const int4 c4 = *(const int4*)&counts[base];
        v0 = c4.x; v1 = c4.y; v2 = c4.z; v3 = c4.w;
    } else {
        if (base + 0 < n) v0 = counts[base + 0];
        if (base + 1 < n) v1 = counts[base + 1];
        if (base + 2 < n) v2 = counts[base + 2];
        if (base + 3 < n) v3 = counts[base + 3];
    }
    const int s4 = v0 + v1 + v2 + v3;
    int incl = s4;
#pragma unroll
    for (int off = 1; off < 64; off <<= 1) {
        const int tt = __shfl_up(incl, off, 64);
        if (lane >= off) incl += tt;
    }
    if (lane == 63) wsum[wid] = incl;
    __syncthreads();
    int wbase = 0;
#pragma unroll
    for (int w = 0; w < 4; ++w) if (w < wid) wbase += wsum[w];
    const int excl = wbase + incl - s4;
    if (base + 0 < n) offsets[base + 0] = excl;
    if (base + 1 < n) offsets[base + 1] = excl + v0;
    if (base + 2 < n) offsets[base + 2] = excl + v0 + v1;
    if (base + 3 < n) offsets[base + 3] = excl + v0 + v1 + v2;
    if (t == 255) blk_sums[blockIdx.x] = wbase + incl;
}

__global__ __launch_bounds__(128) void scan2_k(const int* __restrict__ blk_sums,
        int* __restrict__ blk_off, int* __restrict__ offsets, int nblk, int n) {
    const int t = threadIdx.x;
    const int v = (t < nblk) ? blk_sums[t] : 0;
    int incl = v;
#pragma unroll
    for (int off = 1; off < 64; off <<= 1) {
        const int tt = __shfl_up(incl, off, 64);
        if ((t & 63) >= off) incl += tt;
    }
    __shared__ int w0sum;
    if (t == 63) w0sum = incl;
    __syncthreads();
    int x = incl - v;
    if (t >= 64) x += w0sum;
    if (t < nblk) blk_off[t] = x;
    if (t == nblk - 1) offsets[n] = x + v;
}

__global__ __launch_bounds__(256) void scan3_k(int* __restrict__ offsets,
        int* __restrict__ cursor, const int* __restrict__ blk_off, int n) {
    const int add  = blk_off[blockIdx.x];
    const int base = blockIdx.x * SCHUNK + threadIdx.x * 4;
#pragma unroll
    for (int j = 0; j < 4; ++j) {
        const int i = base + j;
        if (i < n) {
            const int o = offsets[i] + add;
            offsets[i] = o;
            cursor[i]  = o;
        }
    }
}

// windowed scatter: block b handles dst-window (b&7) over edge chunk (b>>3).
__global__ __launch_bounds__(256) void scatter_k(const int* __restrict__ src,
        const int* __restrict__ dst, const int* __restrict__ etype,
        int* __restrict__ cursor, u32* __restrict__ csr_se) {
    const int b  = blockIdx.x;          // 2048 blocks
    const int w  = b & (NWIN - 1);
    const int r  = b >> 3;
    const int lo = w * WNODES, hi = lo + WNODES;
    const int base = r * ECHUNK;
    for (int i = threadIdx.x; i < ECHUNK; i += 256) {
        const int e = base + i;
        const int d = dst[e];
        if (d >= lo && d < hi) {
            const int s   = src[e];
            const int rel = etype[e];
            const int pos = atomicAdd(&cursor[d], 1);
            if (pos >= 0 && pos < N_EDGES)
                csr_se[pos] = (u32)s | ((u32)rel << 17);
        }
    }
}

// --------- edge softmax: compute scores on the fly, write exp (bf16) --------
// 4 nodes per 256-thread block (1 wave/node); lane -> (slot=lane/8, head=lane%8)
__global__ __launch_bounds__(256) void softmax_k(const int* __restrict__ offsets,
        const u32* __restrict__ csr_se,
        const float* __restrict__ eh, const float* __restrict__ et,
        const float* __restrict__ er,
        u16* __restrict__ csr_ab, float* __restrict__ inv_buf) {
    const int n = blockIdx.x * 4 + (threadIdx.x >> 6);
    const int beg = offsets[n], end = offsets[n + 1];
    const int lane = threadIdx.x & 63;
    const int k  = lane & 7;
    const int eo = lane >> 3;
    const float etk = et[n * NHEAD + k];
    float m = -1e30f;
    for (int e = beg + eo; e < end; e += 8) {
        const u32 se = csr_se[e];
        const int s = se & 0x1FFFF;
        const int r = se >> 17;
        float sc = eh[s * NHEAD + k] + etk + er[r * NHEAD + k];
        sc = sc > 0.f ? sc : SLOPE * sc;
        m = fmaxf(m, sc);
    }
    m = fmaxf(m, __shfl_xor(m, 8, 64));
    m = fmaxf(m, __shfl_xor(m, 16, 64));
    m = fmaxf(m, __shfl_xor(m, 32, 64));
    float ssum = 0.f;
    for (int e = beg + eo; e < end; e += 8) {
        const u32 se = csr_se[e];
        const int s = se & 0x1FFFF;
        const int r = se >> 17;
        float sc = eh[s * NHEAD + k] + etk + er[r * NHEAD + k];
        sc = sc > 0.f ? sc : SLOPE * sc;
        const float ex = expf(sc - m);
        csr_ab[(size_t)e * NHEAD + k] = f2bf(ex);
        ssum += ex;
    }
    ssum += __shfl_xor(ssum, 8, 64);
    ssum += __shfl_xor(ssum, 16, 64);
    ssum += __shfl_xor(ssum, 32, 64);
    const float inv = 1.f / fmaxf(ssum, 1e-20f);
    if (lane < 8) inv_buf[n * NHEAD + lane] = inv;
}

// ---------------- one PPR diffusion hop (bf16 f, bf16 a, deferred norm) ----
// v4: wave per node; 16 lanes x 16B cover one 256B row; group's edge word
// loaded by ALL 16 lanes directly (broadcast) -- no ds_bpermute stage.
// Branchless tail via masked meta (se kept in-range, a=0 for invalid).
// Next tile's meta prefetched in named registers before current gathers.
__global__ __launch_bounds__(256) void hop_k(const u16* __restrict__ f_in,
        u16* __restrict__ f_out, const u16* __restrict__ feat0,
        const int* __restrict__ offsets, const u32* __restrict__ csr_se,
        const u16* __restrict__ csr_ab, const float* __restrict__ inv_buf) {
    const int n    = blockIdx.x * 4 + (threadIdx.x >> 6);
    const int lane = threadIdx.x & 63;
    const int li   = lane & 15;     // position within a 256B row (16B each)
    const int grp  = lane >> 4;     // which of 4 concurrent edges
    const int hsel = li >> 1;       // head owning this lane's 8 dims
    const int beg = offsets[n], end = offsets[n + 1];

    float acc[8];
#pragma unroll
    for (int j = 0; j < 8; ++j) acc[j] = 0.f;

    // meta loader: se index masked (in-workspace even when eu >= end),
    // attention coefficient zeroed for invalid slots.
#define LOADM(E, IDX, S_, A_)                                            \
    {                                                                    \
        const int eu = (E) + 4 * (IDX) + grp;                            \
        S_ = csr_se[eu] & 0x1FFFF;                                       \
        const float av = bf2f(csr_ab[(size_t)eu * NHEAD + hsel]);        \
        A_ = (eu < end) ? av : 0.f;                                      \
    }

    int e0 = beg;
    u32 s0 = 0, s1 = 0, s2 = 0, s3 = 0;
    float a0 = 0.f, a1 = 0.f, a2 = 0.f, a3 = 0.f;
    if (e0 < end) {
        LOADM(e0, 0, s0, a0); LOADM(e0, 1, s1, a1);
        LOADM(e0, 2, s2, a2); LOADM(e0, 3, s3, a3);
    }
    for (; e0 < end; e0 += 16) {
        u32 t0 = 0, t1 = 0, t2 = 0, t3 = 0;
        float b0 = 0.f, b1 = 0.f, b2 = 0.f, b3 = 0.f;
        if (e0 + 16 < end) {   // wave-uniform
            LOADM(e0 + 16, 0, t0, b0); LOADM(e0 + 16, 1, t1, b1);
            LOADM(e0 + 16, 2, t2, b2); LOADM(e0 + 16, 3, t3, b3);
        }
        const bf16x8 r0 = *(const bf16x8*)&f_in[(size_t)s0 * DIM + li * 8];
        const bf16x8 r1 = *(const bf16x8*)&f_in[(size_t)s1 * DIM + li * 8];
        const bf16x8 r2 = *(const bf16x8*)&f_in[(size_t)s2 * DIM + li * 8];
        const bf16x8 r3 = *(const bf16x8*)&f_in[(size_t)s3 * DIM + li * 8];
        fma_row(acc, a0, r0);
        fma_row(acc, a1, r1);
        fma_row(acc, a2, r2);
        fma_row(acc, a3, r3);
        s0 = t0; s1 = t1; s2 = t2; s3 = t3;
        a0 = b0; a1 = b1; a2 = b2; a3 = b3;
    }
#undef LOADM
#pragma unroll
    for (int j = 0; j < 8; ++j) {
        acc[j] += __shfl_xor(acc[j], 16, 64);
        acc[j] += __shfl_xor(acc[j], 32, 64);
    }
    if (lane < 16) {
        const float iv = inv_buf[n * NHEAD + hsel];
        const bf16x8 p = *(const bf16x8*)&feat0[(size_t)n * DIM + li * 8];
        bf16x8 o;
#pragma unroll
        for (int j = 0; j < 8; ++j)
            o[j] = (short)f2bf((1.f - ALPHA) * acc[j] * iv + ALPHA * bf2f((u16)p[j]));
        *(bf16x8*)&f_out[(size_t)n * DIM + li * 8] = o;
    }
}

// ---------------- FFN sublayer via MFMA bf16 + residuals, fp32 out ---------
// R4 structure (measured 117us): 32 nodes/block, 256 threads, 2 barriers,
// per-wave LN (8 nodes/wave), prefetched weight frags.
#define YP 136
#define ZP 520
__global__ __launch_bounds__(256) void ffn_k(const u16* __restrict__ f,
        const float* __restrict__ h,
        const float* __restrict__ g2, const float* __restrict__ b2ln,
        const u16* __restrict__ W1s,  // [DFF][DIM] bf16, k-contig
        const float* __restrict__ b1,
        const u16* __restrict__ W2s,  // [DIM][DFF] bf16, k-contig
        const float* __restrict__ b2,
        float* __restrict__ out) {
    __shared__ u16 ysb[32 * YP];
    __shared__ u16 zsb[32 * ZP];

    const int t    = threadIdx.x;
    const int n0b  = blockIdx.x * 32;
    const int wv   = t >> 6;
    const int lane = t & 63;

    // Phase A: per-wave LN of 8 nodes (wave wv -> nodes wv*8..wv*8+7);
    // each node uses 8 lanes x 16 dims; reduce via intra-8-lane shuffles.
    {
        const int nl   = lane >> 3;              // 0..7 node within wave
        const int node = wv * 8 + nl;
        const int cp   = (lane & 7) * 16;        // dim chunk base
        const int gbase = (n0b + node) * DIM + cp;
        float rv[16];
#pragma unroll
        for (int i = 0; i < 4; ++i) {
            const ushort4 fu = *(const ushort4*)&f[gbase + i * 4];
            const float4  hv = *(const float4*)&h[gbase + i * 4];
            rv[i * 4 + 0] = bf2f(fu.x) + hv.x;
            rv[i * 4 + 1] = bf2f(fu.y) + hv.y;
            rv[i * 4 + 2] = bf2f(fu.z) + hv.z;
            rv[i * 4 + 3] = bf2f(fu.w) + hv.w;
        }
        float s = 0.f, q = 0.f;
#pragma unroll
        for (int i = 0; i < 16; ++i) { s += rv[i]; q += rv[i] * rv[i]; }
        s += __shfl_xor(s, 1, 64); q += __shfl_xor(q, 1, 64);
        s += __shfl_xor(s, 2, 64); q += __shfl_xor(q, 2, 64);
        s += __shfl_xor(s, 4, 64); q += __shfl_xor(q, 4, 64);
        const float mu  = s * (1.0f / 128.0f);
        const float var = q * (1.0f / 128.0f) - mu * mu;
        const float rs  = rsqrtf(fmaxf(var, 0.f) + LN_EPS);
#pragma unroll
        for (int i = 0; i < 4; ++i) {
            ushort4 yo;
            const int c = cp + i * 4;
            yo.x = f2bf((rv[i*4+0] - mu) * rs * g2[c+0] + b2ln[c+0]);
            yo.y = f2bf((rv[i*4+1] - mu) * rs * g2[c+1] + b2ln[c+1]);
            yo.z = f2bf((rv[i*4+2] - mu) * rs * g2[c+2] + b2ln[c+2]);
            yo.w = f2bf((rv[i*4+3] - mu) * rs * g2[c+3] + b2ln[c+3]);
            *(ushort4*)&ysb[node * YP + c] = yo;
        }
    }
    __syncthreads();

    const int lm = lane & 15;
    const int q4 = lane >> 4;

    // Phase B: z = relu(y @ W1), wave wv -> z-cols [wv*128, wv*128+128)
    {
        bf16x8 afr[2][4];
#pragma unroll
        for (int mt = 0; mt < 2; ++mt)
#pragma unroll
            for (int kt = 0; kt < 4; ++kt)
                afr[mt][kt] = *(const bf16x8*)&ysb[(mt * 16 + lm) * YP + kt * 32 + q4 * 8];

        const int cw = wv * 128;
        bf16x8 bc[4];
#pragma unroll
        for (int kt = 0; kt < 4; ++kt)
            bc[kt] = *(const bf16x8*)&W1s[(cw + lm) * DIM + kt * 32 + q4 * 8];

#pragma unroll
        for (int nt = 0; nt < 8; ++nt) {
            const int n0 = cw + nt * 16;
            bf16x8 bn[4] = {bc[0], bc[1], bc[2], bc[3]};
            if (nt < 7) {
#pragma unroll
                for (int kt = 0; kt < 4; ++kt)
                    bn[kt] = *(const bf16x8*)&W1s[(n0 + 16 + lm) * DIM + kt * 32 + q4 * 8];
            }
            f32x4 acc0 = {0.f, 0.f, 0.f, 0.f};
            f32x4 acc1 = {0.f, 0.f, 0.f, 0.f};
#pragma unroll
            for (int kt = 0; kt < 4; ++kt) {
                acc0 = __builtin_amdgcn_mfma_f32_16x16x32_bf16(afr[0][kt], bc[kt], acc0, 0, 0, 0);
                acc1 = __builtin_amdgcn_mfma_f32_16x16x32_bf16(afr[1][kt], bc[kt], acc1, 0, 0, 0);
            }
            const float bias = b1[n0 + lm];
#pragma unroll
            for (int r = 0; r < 4; ++r) {
                zsb[(q4 * 4 + r) * ZP + n0 + lm]      = f2bf(fmaxf(acc0[r] + bias, 0.f));
                zsb[(16 + q4 * 4 + r) * ZP + n0 + lm] = f2bf(fmaxf(acc1[r] + bias, 0.f));
            }
#pragma unroll
            for (int kt = 0; kt < 4; ++kt) bc[kt] = bn[kt];
        }
    }
    __syncthreads();

    // Phase C: out = z @ W2 (+bias +residuals), wave wv -> out-cols [wv*32,+32)
    f32x4 acc[2][2];
#pragma unroll
    for (int i = 0; i < 2; ++i)
#pragma unroll
        for (int j = 0; j < 2; ++j)
            acc[i][j] = (f32x4){0.f, 0.f, 0.f, 0.f};
    const int c0 = wv * 32;
    bf16x8 wc0 = *(const bf16x8*)&W2s[(c0 + lm) * DFF + q4 * 8];
    bf16x8 wc1 = *(const bf16x8*)&W2s[(c0 + 16 + lm) * DFF + q4 * 8];
#pragma unroll
    for (int kt = 0; kt < 16; ++kt) {
        bf16x8 wn0 = wc0, wn1 = wc1;
        if (kt < 15) {
            wn0 = *(const bf16x8*)&W2s[(c0 + lm) * DFF + (kt + 1) * 32 + q4 * 8];
            wn1 = *(const bf16x8*)&W2s[(c0 + 16 + lm) * DFF + (kt + 1) * 32 + q4 * 8];
        }
        const bf16x8 a0 = *(const bf16x8*)&zsb[(lm) * ZP + kt * 32 + q4 * 8];
        const bf16x8 a1 = *(const bf16x8*)&zsb[(16 + lm) * ZP + kt * 32 + q4 * 8];
        acc[0][0] = __builtin_amdgcn_mfma_f32_16x16x32_bf16(a0, wc0, acc[0][0], 0, 0, 0);
        acc[0][1] = __builtin_amdgcn_mfma_f32_16x16x32_bf16(a0, wc1, acc[0][1], 0, 0, 0);
        acc[1][0] = __builtin_amdgcn_mfma_f32_16x16x32_bf16(a1, wc0, acc[1][0], 0, 0, 0);
        acc[1][1] = __builtin_amdgcn_mfma_f32_16x16x32_bf16(a1, wc1, acc[1][1], 0, 0, 0);
        wc0 = wn0; wc1 = wn1;
    }

#pragma unroll
    for (int ntile = 0; ntile < 2; ++ntile) {
        const int col = c0 + ntile * 16 + lm;
        const float bias = b2[col];
#pragma unroll
        for (int mt = 0; mt < 2; ++mt) {
#pragma unroll
            for (int r = 0; r < 4; ++r) {
                const int row  = mt * 16 + q4 * 4 + r;
                const int gidx = (n0b + row) * DIM + col;
                out[gidx] = acc[mt][ntile][r] + bias + bf2f(f[gidx]) + h[gidx];
            }
        }
    }
}

// ---------------------------------------------------------------------------
extern "C" void kernel_launch(void* const* d_in, const int* in_sizes, int n_in,
                              void* d_out, int out_size, void* d_ws, size_t ws_size,
                              hipStream_t stream) {
    const float* ent_feat = (const float*)d_in[0];
    const float* rel_feat = (const float*)d_in[1];
    const int*   src      = (const int*)d_in[2];
    const int*   dst      = (const int*)d_in[3];
    const int*   e_type   = (const int*)d_in[4];
    const float* ln1_g    = (const float*)d_in[5];
    const float* ln1_b    = (const float*)d_in[6];
    const float* W_ent    = (const float*)d_in[7];
    const float* W_rel    = (const float*)d_in[8];
    const float* attn_h   = (const float*)d_in[9];
    const float* attn_t   = (const float*)d_in[10];
    const float* attn_r   = (const float*)d_in[11];
    const float* ln2_g    = (const float*)d_in[12];
    const float* ln2_b    = (const float*)d_in[13];
    const float* W1       = (const float*)d_in[14];
    const float* b1       = (const float*)d_in[15];
    const float* W2       = (const float*)d_in[16];
    const float* b2       = (const float*)d_in[17];
    float* out = (float*)d_out;

    char* ws = (char*)d_ws;
    size_t used = 0;
    auto alloc = [&](size_t bytes) -> char* {
        char* p = ws + used;
        used += (bytes + 255) & ~(size_t)255;
        return p;
    };
    float* h       = (float*)alloc((size_t)N_NODES * DIM * 4);   // 51.2 MB
    u16*   feat0   = (u16*)  alloc((size_t)N_NODES * DIM * 2);   // 25.6 MB
    u16*   fA      = (u16*)  alloc((size_t)N_NODES * DIM * 2);   // 25.6 MB
    u16*   fB      = (u16*)  alloc((size_t)N_NODES * DIM * 2);   // 25.6 MB
    u16*   csr_ab  = (u16*)  alloc((size_t)N_EDGES * NHEAD * 2); // 25.6 MB
    float* eh      = (float*)alloc((size_t)N_NODES * NHEAD * 4); // 3.2 MB
    float* et      = (float*)alloc((size_t)N_NODES * NHEAD * 4); // 3.2 MB
    float* inv_buf = (float*)alloc((size_t)N_NODES * NHEAD * 4); // 3.2 MB
    u32*   csr_se  = (u32*)  alloc((size_t)N_EDGES * 4);         // 6.4 MB
    int*   counts  = (int*)  alloc((size_t)N_NODES * 4);
    int*   offsets = (int*)  alloc((size_t)(N_NODES + 1) * 4);
    int*   cursor  = (int*)  alloc((size_t)N_NODES * 4);
    float* er      = (float*)alloc((size_t)N_REL * NHEAD * 4);
    u16*   W1s     = (u16*)  alloc((size_t)DIM * DFF * 2);
    u16*   W2s     = (u16*)  alloc((size_t)DFF * DIM * 2);
    u16*   Wes     = (u16*)  alloc((size_t)DIM * DIM * 2);
    int*   blk_sums= (int*)  alloc((size_t)NSCANBLK * 4);
    int*   blk_off = (int*)  alloc((size_t)NSCANBLK * 4);

    if (used > ws_size) return;   // diagnostic: absmax == max|ref|

    swz1_k<<<DIM * DFF / 256, 256, 0, stream>>>(W1, W1s);
    swz2_k<<<DFF * DIM / 256, 256, 0, stream>>>(W2, W2s);
    swze_k<<<DIM * DIM / 256, 256, 0, stream>>>(W_ent, Wes);

    ln1_k<<<N_NODES, 128, 0, stream>>>(ent_feat, ln1_g, ln1_b, h);
    proj_k<<<N_NODES / 32, 256, 0, stream>>>(h, Wes, feat0);
    eh_k<<<N_NODES * NHEAD / 256, 256, 0, stream>>>(feat0, attn_h, attn_t, eh, et);
    rel_k<<<N_REL, 128, 0, stream>>>(rel_feat, W_rel, attn_r, er);

    zero_k<<<(N_NODES + 255) / 256, 256, 0, stream>>>(counts, N_NODES);
    count_k<<<(N_EDGES + 255) / 256, 256, 0, stream>>>(dst, counts);
    scan1_k<<<NSCANBLK, 256, 0, stream>>>(counts, offsets, blk_sums, N_NODES);
    scan2_k<<<1, 128, 0, stream>>>(blk_sums, blk_off, offsets, NSCANBLK, N_NODES);
    scan3_k<<<NSCANBLK, 256, 0, stream>>>(offsets, cursor, blk_off, N_NODES);
    scatter_k<<<NECHUNK * NWIN, 256, 0, stream>>>(src, dst, e_type,
                                                  cursor, csr_se);
    softmax_k<<<N_NODES / 4, 256, 0, stream>>>(offsets, csr_se, eh, et, er,
                                               csr_ab, inv_buf);

    // 5 PPR hops: feat0 -> fA -> fB -> fA -> fB -> fA
    hop_k<<<N_NODES / 4, 256, 0, stream>>>(feat0, fA, feat0, offsets, csr_se, csr_ab, inv_buf);
    hop_k<<<N_NODES / 4, 256, 0, stream>>>(fA, fB, feat0, offsets, csr_se, csr_ab, inv_buf);
    hop_k<<<N_NODES / 4, 256, 0, stream>>>(fB, fA, feat0, offsets, csr_se, csr_ab, inv_buf);
    hop_k<<<N_NODES / 4, 256, 0, stream>>>(fA, fB, feat0, offsets, csr_se, csr_ab, inv_buf);
    hop_k<<<N_NODES / 4, 256, 0, stream>>>(fB, fA, feat0, offsets, csr_se, csr_ab, inv_buf);

    // FFN + residuals (MFMA)
    ffn_k<<<N_NODES / 32, 256, 0, stream>>>(fA, h, ln2_g, ln2_b, W1s, b1, W2s, b2,
                                            out);
}

// Round 8
// 880.031 us; speedup vs baseline: 1.2009x; 1.0092x over previous
//
#include <hip/hip_runtime.h>
#include <hip/hip_bf16.h>
#include <math.h>

#define N_NODES 100000
#define N_EDGES 1600000
#define N_REL   500
#define DIM     128
#define NHEAD   8
#define DFF     512
#define ALPHA   0.15f
#define SLOPE   0.2f
#define LN_EPS  1e-5f

#define SCHUNK   1024
#define NSCANBLK ((N_NODES + SCHUNK - 1) / SCHUNK)   // 98

// windowed scatter: 8 windows of 12500 nodes; 256 edge chunks of 6250
#define NWIN    8
#define WNODES  12500
#define NECHUNK 256
#define ECHUNK  (N_EDGES / NECHUNK)   // 6250

typedef unsigned short u16;
typedef unsigned int   u32;

typedef __attribute__((ext_vector_type(8))) short  bf16x8;   // MFMA A/B frag
typedef __attribute__((ext_vector_type(4))) float  f32x4;    // MFMA C/D frag

__device__ __forceinline__ float bf2f(u16 u) {
    return __uint_as_float(((u32)u) << 16);
}
__device__ __forceinline__ u16 f2bf(float f) {
    __hip_bfloat16 b = __float2bfloat16(f);
    return *reinterpret_cast<u16*>(&b);
}

// paired bf16 extraction: 1 VALU + 1 FMA per element
__device__ __forceinline__ void fma_row(float* acc, float a, const bf16x8& r) {
    const u32* w = (const u32*)&r;
#pragma unroll
    for (int jj = 0; jj < 4; ++jj) {
        acc[2 * jj]     += a * __uint_as_float(w[jj] << 16);
        acc[2 * jj + 1] += a * __uint_as_float(w[jj] & 0xffff0000u);
    }
}

// ---------------- zero an int buffer (graph-capture-safe memset) ------------
__global__ void zero_k(int* __restrict__ p, int n) {
    int i = blockIdx.x * blockDim.x + threadIdx.x;
    if (i < n) p[i] = 0;
}

// ------ weight pre-swizzles to bf16, k-contiguous [n][k] --------------------
__global__ void swz1_k(const float* __restrict__ W1, u16* __restrict__ W1s) {
    const int i = blockIdx.x * 256 + threadIdx.x;       // 65536
    const int k = i >> 9, n = i & 511;
    W1s[n * DIM + k] = f2bf(W1[i]);
}
__global__ void swz2_k(const float* __restrict__ W2, u16* __restrict__ W2s) {
    const int i = blockIdx.x * 256 + threadIdx.x;       // 65536
    const int k = i >> 7, n = i & 127;
    W2s[n * DFF + k] = f2bf(W2[i]);
}
__global__ void swze_k(const float* __restrict__ W, u16* __restrict__ Ws) {
    const int i = blockIdx.x * 256 + threadIdx.x;       // 16384
    const int k = i >> 7, n = i & 127;
    Ws[n * DIM + k] = f2bf(W[i]);
}

// ------- LayerNorm 1 : h = LN(ent_feat), stored bf16 (halves h traffic) -----
__global__ __launch_bounds__(128) void ln1_k(const float* __restrict__ x,
        const float* __restrict__ g, const float* __restrict__ b,
        u16* __restrict__ h) {
    const int n = blockIdx.x, t = threadIdx.x;
    const float v = x[n * DIM + t];
    float s = v, q = v * v;
#pragma unroll
    for (int off = 32; off > 0; off >>= 1) {
        s += __shfl_xor(s, off, 64);
        q += __shfl_xor(q, off, 64);
    }
    __shared__ float ss[2], qq[2];
    if ((t & 63) == 0) { ss[t >> 6] = s; qq[t >> 6] = q; }
    __syncthreads();
    s = ss[0] + ss[1]; q = qq[0] + qq[1];
    const float mu  = s * (1.0f / 128.0f);
    const float var = q * (1.0f / 128.0f) - mu * mu;
    const float rs  = rsqrtf(fmaxf(var, 0.f) + LN_EPS);
    h[n * DIM + t] = f2bf((v - mu) * rs * g[t] + b[t]);
}

// --------- feat0 = h @ W_ent via MFMA bf16 (32 nodes/block, 4 waves) --------
#define HP 136   // hsb row pitch (u16), 136 = 8*17 (keeps 16B frag alignment)
__global__ __launch_bounds__(256) void proj_k(const u16* __restrict__ h,
        const u16* __restrict__ Wes,  // [DIM n][DIM k] bf16, k-contig
        u16* __restrict__ feat0) {
    __shared__ u16 hsb[32 * HP];
    const int t   = threadIdx.x;
    const int n0b = blockIdx.x * 32;

    // stage h (already bf16) into LDS: thread t -> row t>>3, 16 cols (32B)
    {
        const int sr = t >> 3;
        const int sc = (t & 7) * 16;
        const u16* hrow = &h[(size_t)(n0b + sr) * DIM + sc];
        u16* drow = &hsb[sr * HP + sc];
        ((uint4*)drow)[0] = ((const uint4*)hrow)[0];
        ((uint4*)drow)[1] = ((const uint4*)hrow)[1];
    }
    __syncthreads();

    const int wv   = t >> 6;
    const int lane = t & 63;
    const int lm   = lane & 15;
    const int q4   = lane >> 4;
    const int mrow = (wv & 1) * 16;        // rows [mrow, mrow+16)
    const int chalf = (wv >> 1) * 64;      // cols [chalf, chalf+64)

    bf16x8 afr[4];
#pragma unroll
    for (int kt = 0; kt < 4; ++kt)
        afr[kt] = *(const bf16x8*)&hsb[(mrow + lm) * HP + kt * 32 + q4 * 8];

#pragma unroll
    for (int nt = 0; nt < 4; ++nt) {
        const int c0 = chalf + nt * 16;
        f32x4 acc = {0.f, 0.f, 0.f, 0.f};
#pragma unroll
        for (int kt = 0; kt < 4; ++kt) {
            const bf16x8 bfr = *(const bf16x8*)&Wes[(c0 + lm) * DIM + kt * 32 + q4 * 8];
            acc = __builtin_amdgcn_mfma_f32_16x16x32_bf16(afr[kt], bfr, acc, 0, 0, 0);
        }
#pragma unroll
        for (int r = 0; r < 4; ++r)
            feat0[(size_t)(n0b + mrow + q4 * 4 + r) * DIM + c0 + lm] = f2bf(acc[r]);
    }
}

// --------- eh/et: per-head attn dots from feat0 -----------------------------
__global__ __launch_bounds__(256) void eh_k(const u16* __restrict__ feat0,
        const float* __restrict__ attn_h, const float* __restrict__ attn_t,
        float* __restrict__ eh, float* __restrict__ et) {
    __shared__ float ahs[DIM], ats[DIM];
    const int t = threadIdx.x;
    if (t < DIM) { ahs[t] = attn_h[t]; ats[t] = attn_t[t]; }
    __syncthreads();
    const int idx  = blockIdx.x * 256 + t;
    const int n    = idx >> 3;
    const int head = idx & 7;
    const u16* fp = &feat0[(size_t)n * DIM + head * 16];
    float sh = 0.f, st = 0.f;
#pragma unroll
    for (int i = 0; i < 4; ++i) {
        const ushort4 f4 = ((const ushort4*)fp)[i];
        const int c = head * 16 + i * 4;
        sh += bf2f(f4.x) * ahs[c+0] + bf2f(f4.y) * ahs[c+1]
            + bf2f(f4.z) * ahs[c+2] + bf2f(f4.w) * ahs[c+3];
        st += bf2f(f4.x) * ats[c+0] + bf2f(f4.y) * ats[c+1]
            + bf2f(f4.z) * ats[c+2] + bf2f(f4.w) * ats[c+3];
    }
    eh[idx] = sh;
    et[idx] = st;
}

// ---------------- er[r][head] = ((rel_feat @ W_rel) * attn_r).sum ----------
__global__ __launch_bounds__(128) void rel_k(const float* __restrict__ rel_feat,
        const float* __restrict__ W,
        const float* __restrict__ attn_r, float* __restrict__ er) {
    __shared__ float rf[DIM];
    __shared__ float pr[DIM];
    const int r = blockIdx.x, t = threadIdx.x;
    rf[t] = rel_feat[r * DIM + t];
    __syncthreads();
    float acc = 0.f;
    for (int d = 0; d < DIM; ++d) acc += rf[d] * W[d * DIM + t];
    pr[t] = acc * attn_r[t];
    __syncthreads();
    if (t < NHEAD) {
        float s = 0.f;
        for (int i = 0; i < 16; ++i) s += pr[t * 16 + i];
        er[r * NHEAD + t] = s;
    }
}

// ---------------- CSR build: histogram, 3-phase scan, scatter ---------------
__global__ void count_k(const int* __restrict__ dst, int* __restrict__ counts) {
    int e = blockIdx.x * blockDim.x + threadIdx.x;
    if (e < N_EDGES) atomicAdd(&counts[dst[e]], 1);
}

__global__ __launch_bounds__(256) void scan1_k(const int* __restrict__ counts,
        int* __restrict__ offsets, int* __restrict__ blk_sums, int n) {
    __shared__ int wsum[4];
    const int t = threadIdx.x, lane = t & 63, wid = t >> 6;
    const int base = blockIdx.x * SCHUNK + t * 4;
    int v0 = 0, v1 = 0, v2 = 0, v3 = 0;
    if (base + 3 < n) {
        const int4 c4 = *(const int4*)&counts[base];
        v0 = c4.x; v1 = c4.y; v2 = c4.z; v3 = c4.w;
    } else {
        if (base + 0 < n) v0 = counts[base + 0];
        if (base + 1 < n) v1 = counts[base + 1];
        if (base + 2 < n) v2 = counts[base + 2];
        if (base + 3 < n) v3 = counts[base + 3];
    }
    const int s4 = v0 + v1 + v2 + v3;
    int incl = s4;
#pragma unroll
    for (int off = 1; off < 64; off <<= 1) {
        const int tt = __shfl_up(incl, off, 64);
        if (lane >= off) incl += tt;
    }
    if (lane == 63) wsum[wid] = incl;
    __syncthreads();
    int wbase = 0;
#pragma unroll
    for (int w = 0; w < 4; ++w) if (w < wid) wbase += wsum[w];
    const int excl = wbase + incl - s4;
    if (base + 0 < n) offsets[base + 0] = excl;
    if (base + 1 < n) offsets[base + 1] = excl + v0;
    if (base + 2 < n) offsets[base + 2] = excl + v0 + v1;
    if (base + 3 < n) offsets[base + 3] = excl + v0 + v1 + v2;
    if (t == 255) blk_sums[blockIdx.x] = wbase + incl;
}

__global__ __launch_bounds__(128) void scan2_k(const int* __restrict__ blk_sums,
        int* __restrict__ blk_off, int* __restrict__ offsets, int nblk, int n) {
    const int t = threadIdx.x;
    const int v = (t < nblk) ? blk_sums[t] : 0;
    int incl = v;
#pragma unroll
    for (int off = 1; off < 64; off <<= 1) {
        const int tt = __shfl_up(incl, off, 64);
        if ((t & 63) >= off) incl += tt;
    }
    __shared__ int w0sum;
    if (t == 63) w0sum = incl;
    __syncthreads();
    int x = incl - v;
    if (t >= 64) x += w0sum;
    if (t < nblk) blk_off[t] = x;
    if (t == nblk - 1) offsets[n] = x + v;
}

__global__ __launch_bounds__(256) void scan3_k(int* __restrict__ offsets,
        int* __restrict__ cursor, const int* __restrict__ blk_off, int n) {
    const int add  = blk_off[blockIdx.x];
    const int base = blockIdx.x * SCHUNK + threadIdx.x * 4;
#pragma unroll
    for (int j = 0; j < 4; ++j) {
        const int i = base + j;
        if (i < n) {
            const int o = offsets[i] + add;
            offsets[i] = o;
            cursor[i]  = o;
        }
    }
}

// windowed scatter: block b handles dst-window (b&7) over edge chunk (b>>3).
__global__ __launch_bounds__(256) void scatter_k(const int* __restrict__ src,
        const int* __restrict__ dst, const int* __restrict__ etype,
        int* __restrict__ cursor, u32* __restrict__ csr_se) {
    const int b  = blockIdx.x;          // 2048 blocks
    const int w  = b & (NWIN - 1);
    const int r  = b >> 3;
    const int lo = w * WNODES, hi = lo + WNODES;
    const int base = r * ECHUNK;
    for (int i = threadIdx.x; i < ECHUNK; i += 256) {
        const int e = base + i;
        const int d = dst[e];
        if (d >= lo && d < hi) {
            const int s   = src[e];
            const int rel = etype[e];
            const int pos = atomicAdd(&cursor[d], 1);
            if (pos >= 0 && pos < N_EDGES)
                csr_se[pos] = (u32)s | ((u32)rel << 17);
        }
    }
}

// --------- edge softmax: compute scores on the fly, write exp (bf16) --------
// 4 nodes per 256-thread block (1 wave/node); lane -> (slot=lane/8, head=lane%8)
__global__ __launch_bounds__(256) void softmax_k(const int* __restrict__ offsets,
        const u32* __restrict__ csr_se,
        const float* __restrict__ eh, const float* __restrict__ et,
        const float* __restrict__ er,
        u16* __restrict__ csr_ab, float* __restrict__ inv_buf) {
    const int n = blockIdx.x * 4 + (threadIdx.x >> 6);
    const int beg = offsets[n], end = offsets[n + 1];
    const int lane = threadIdx.x & 63;
    const int k  = lane & 7;
    const int eo = lane >> 3;
    const float etk = et[n * NHEAD + k];
    float m = -1e30f;
    for (int e = beg + eo; e < end; e += 8) {
        const u32 se = csr_se[e];
        const int s = se & 0x1FFFF;
        const int r = se >> 17;
        float sc = eh[s * NHEAD + k] + etk + er[r * NHEAD + k];
        sc = sc > 0.f ? sc : SLOPE * sc;
        m = fmaxf(m, sc);
    }
    m = fmaxf(m, __shfl_xor(m, 8, 64));
    m = fmaxf(m, __shfl_xor(m, 16, 64));
    m = fmaxf(m, __shfl_xor(m, 32, 64));
    float ssum = 0.f;
    for (int e = beg + eo; e < end; e += 8) {
        const u32 se = csr_se[e];
        const int s = se & 0x1FFFF;
        const int r = se >> 17;
        float sc = eh[s * NHEAD + k] + etk + er[r * NHEAD + k];
        sc = sc > 0.f ? sc : SLOPE * sc;
        const float ex = expf(sc - m);
        csr_ab[(size_t)e * NHEAD + k] = f2bf(ex);
        ssum += ex;
    }
    ssum += __shfl_xor(ssum, 8, 64);
    ssum += __shfl_xor(ssum, 16, 64);
    ssum += __shfl_xor(ssum, 32, 64);
    const float inv = 1.f / fmaxf(ssum, 1e-20f);
    if (lane < 8) inv_buf[n * NHEAD + lane] = inv;
}

// ---------------- one PPR diffusion hop (bf16 f, bf16 a, deferred norm) ----
// v4: wave per node; 16 lanes x 16B cover one 256B row; group's edge word
// loaded by ALL 16 lanes directly (broadcast) -- no ds_bpermute stage.
__global__ __launch_bounds__(256) void hop_k(const u16* __restrict__ f_in,
        u16* __restrict__ f_out, const u16* __restrict__ feat0,
        const int* __restrict__ offsets, const u32* __restrict__ csr_se,
        const u16* __restrict__ csr_ab, const float* __restrict__ inv_buf) {
    const int n    = blockIdx.x * 4 + (threadIdx.x >> 6);
    const int lane = threadIdx.x & 63;
    const int li   = lane & 15;     // position within a 256B row (16B each)
    const int grp  = lane >> 4;     // which of 4 concurrent edges
    const int hsel = li >> 1;       // head owning this lane's 8 dims
    const int beg = offsets[n], end = offsets[n + 1];

    float acc[8];
#pragma unroll
    for (int j = 0; j < 8; ++j) acc[j] = 0.f;

#define LOADM(E, IDX, S_, A_)                                            \
    {                                                                    \
        const int eu = (E) + 4 * (IDX) + grp;                            \
        S_ = csr_se[eu] & 0x1FFFF;                                       \
        const float av = bf2f(csr_ab[(size_t)eu * NHEAD + hsel]);        \
        A_ = (eu < end) ? av : 0.f;                                      \
    }

    int e0 = beg;
    u32 s0 = 0, s1 = 0, s2 = 0, s3 = 0;
    float a0 = 0.f, a1 = 0.f, a2 = 0.f, a3 = 0.f;
    if (e0 < end) {
        LOADM(e0, 0, s0, a0); LOADM(e0, 1, s1, a1);
        LOADM(e0, 2, s2, a2); LOADM(e0, 3, s3, a3);
    }
    for (; e0 < end; e0 += 16) {
        u32 t0 = 0, t1 = 0, t2 = 0, t3 = 0;
        float b0 = 0.f, b1 = 0.f, b2 = 0.f, b3 = 0.f;
        if (e0 + 16 < end) {   // wave-uniform
            LOADM(e0 + 16, 0, t0, b0); LOADM(e0 + 16, 1, t1, b1);
            LOADM(e0 + 16, 2, t2, b2); LOADM(e0 + 16, 3, t3, b3);
        }
        const bf16x8 r0 = *(const bf16x8*)&f_in[(size_t)s0 * DIM + li * 8];
        const bf16x8 r1 = *(const bf16x8*)&f_in[(size_t)s1 * DIM + li * 8];
        const bf16x8 r2 = *(const bf16x8*)&f_in[(size_t)s2 * DIM + li * 8];
        const bf16x8 r3 = *(const bf16x8*)&f_in[(size_t)s3 * DIM + li * 8];
        fma_row(acc, a0, r0);
        fma_row(acc, a1, r1);
        fma_row(acc, a2, r2);
        fma_row(acc, a3, r3);
        s0 = t0; s1 = t1; s2 = t2; s3 = t3;
        a0 = b0; a1 = b1; a2 = b2; a3 = b3;
    }
#undef LOADM
#pragma unroll
    for (int j = 0; j < 8; ++j) {
        acc[j] += __shfl_xor(acc[j], 16, 64);
        acc[j] += __shfl_xor(acc[j], 32, 64);
    }
    if (lane < 16) {
        const float iv = inv_buf[n * NHEAD + hsel];
        const bf16x8 p = *(const bf16x8*)&feat0[(size_t)n * DIM + li * 8];
        bf16x8 o;
#pragma unroll
        for (int j = 0; j < 8; ++j)
            o[j] = (short)f2bf((1.f - ALPHA) * acc[j] * iv + ALPHA * bf2f((u16)p[j]));
        *(bf16x8*)&f_out[(size_t)n * DIM + li * 8] = o;
    }
}

// ---------------- FFN sublayer via MFMA bf16 + residuals, fp32 out ---------
// R4 structure (measured 117us); h is now bf16 (halved fetch).
#define YP 136
#define ZP 520
__global__ __launch_bounds__(256) void ffn_k(const u16* __restrict__ f,
        const u16* __restrict__ h,
        const float* __restrict__ g2, const float* __restrict__ b2ln,
        const u16* __restrict__ W1s,  // [DFF][DIM] bf16, k-contig
        const float* __restrict__ b1,
        const u16* __restrict__ W2s,  // [DIM][DFF] bf16, k-contig
        const float* __restrict__ b2,
        float* __restrict__ out) {
    __shared__ u16 ysb[32 * YP];
    __shared__ u16 zsb[32 * ZP];

    const int t    = threadIdx.x;
    const int n0b  = blockIdx.x * 32;
    const int wv   = t >> 6;
    const int lane = t & 63;

    // Phase A: per-wave LN of 8 nodes (wave wv -> nodes wv*8..wv*8+7);
    // each node uses 8 lanes x 16 dims; reduce via intra-8-lane shuffles.
    {
        const int nl   = lane >> 3;              // 0..7 node within wave
        const int node = wv * 8 + nl;
        const int cp   = (lane & 7) * 16;        // dim chunk base
        const int gbase = (n0b + node) * DIM + cp;
        float rv[16];
#pragma unroll
        for (int i = 0; i < 4; ++i) {
            const ushort4 fu = *(const ushort4*)&f[gbase + i * 4];
            const ushort4 hu = *(const ushort4*)&h[gbase + i * 4];
            rv[i * 4 + 0] = bf2f(fu.x) + bf2f(hu.x);
            rv[i * 4 + 1] = bf2f(fu.y) + bf2f(hu.y);
            rv[i * 4 + 2] = bf2f(fu.z) + bf2f(hu.z);
            rv[i * 4 + 3] = bf2f(fu.w) + bf2f(hu.w);
        }
        float s = 0.f, q = 0.f;
#pragma unroll
        for (int i = 0; i < 16; ++i) { s += rv[i]; q += rv[i] * rv[i]; }
        s += __shfl_xor(s, 1, 64); q += __shfl_xor(q, 1, 64);
        s += __shfl_xor(s, 2, 64); q += __shfl_xor(q, 2, 64);
        s += __shfl_xor(s, 4, 64); q += __shfl_xor(q, 4, 64);
        const float mu  = s * (1.0f / 128.0f);
        const float var = q * (1.0f / 128.0f) - mu * mu;
        const float rs  = rsqrtf(fmaxf(var, 0.f) + LN_EPS);
#pragma unroll
        for (int i = 0; i < 4; ++i) {
            ushort4 yo;
            const int c = cp + i * 4;
            yo.x = f2bf((rv[i*4+0] - mu) * rs * g2[c+0] + b2ln[c+0]);
            yo.y = f2bf((rv[i*4+1] - mu) * rs * g2[c+1] + b2ln[c+1]);
            yo.z = f2bf((rv[i*4+2] - mu) * rs * g2[c+2] + b2ln[c+2]);
            yo.w = f2bf((rv[i*4+3] - mu) * rs * g2[c+3] + b2ln[c+3]);
            *(ushort4*)&ysb[node * YP + c] = yo;
        }
    }
    __syncthreads();

    const int lm = lane & 15;
    const int q4 = lane >> 4;

    // Phase B: z = relu(y @ W1), wave wv -> z-cols [wv*128, wv*128+128)
    {
        bf16x8 afr[2][4];
#pragma unroll
        for (int mt = 0; mt < 2; ++mt)
#pragma unroll
            for (int kt = 0; kt < 4; ++kt)
                afr[mt][kt] = *(const bf16x8*)&ysb[(mt * 16 + lm) * YP + kt * 32 + q4 * 8];

        const int cw = wv * 128;
        bf16x8 bc[4];
#pragma unroll
        for (int kt = 0; kt < 4; ++kt)
            bc[kt] = *(const bf16x8*)&W1s[(cw + lm) * DIM + kt * 32 + q4 * 8];

#pragma unroll
        for (int nt = 0; nt < 8; ++nt) {
            const int n0 = cw + nt * 16;
            bf16x8 bn[4] = {bc[0], bc[1], bc[2], bc[3]};
            if (nt < 7) {
#pragma unroll
                for (int kt = 0; kt < 4; ++kt)
                    bn[kt] = *(const bf16x8*)&W1s[(n0 + 16 + lm) * DIM + kt * 32 + q4 * 8];
            }
            f32x4 acc0 = {0.f, 0.f, 0.f, 0.f};
            f32x4 acc1 = {0.f, 0.f, 0.f, 0.f};
#pragma unroll
            for (int kt = 0; kt < 4; ++kt) {
                acc0 = __builtin_amdgcn_mfma_f32_16x16x32_bf16(afr[0][kt], bc[kt], acc0, 0, 0, 0);
                acc1 = __builtin_amdgcn_mfma_f32_16x16x32_bf16(afr[1][kt], bc[kt], acc1, 0, 0, 0);
            }
            const float bias = b1[n0 + lm];
#pragma unroll
            for (int r = 0; r < 4; ++r) {
                zsb[(q4 * 4 + r) * ZP + n0 + lm]      = f2bf(fmaxf(acc0[r] + bias, 0.f));
                zsb[(16 + q4 * 4 + r) * ZP + n0 + lm] = f2bf(fmaxf(acc1[r] + bias, 0.f));
            }
#pragma unroll
            for (int kt = 0; kt < 4; ++kt) bc[kt] = bn[kt];
        }
    }
    __syncthreads();

    // Phase C: out = z @ W2 (+bias +residuals), wave wv -> out-cols [wv*32,+32)
    f32x4 acc[2][2];
#pragma unroll
    for (int i = 0; i < 2; ++i)
#pragma unroll
        for (int j = 0; j < 2; ++j)
            acc[i][j] = (f32x4){0.f, 0.f, 0.f, 0.f};
    const int c0 = wv * 32;
    bf16x8 wc0 = *(const bf16x8*)&W2s[(c0 + lm) * DFF + q4 * 8];
    bf16x8 wc1 = *(const bf16x8*)&W2s[(c0 + 16 + lm) * DFF + q4 * 8];
#pragma unroll
    for (int kt = 0; kt < 16; ++kt) {
        bf16x8 wn0 = wc0, wn1 = wc1;
        if (kt < 15) {
            wn0 = *(const bf16x8*)&W2s[(c0 + lm) * DFF + (kt + 1) * 32 + q4 * 8];
            wn1 = *(const bf16x8*)&W2s[(c0 + 16 + lm) * DFF + (kt + 1) * 32 + q4 * 8];
        }
        const bf16x8 a0 = *(const bf16x8*)&zsb[(lm) * ZP + kt * 32 + q4 * 8];
        const bf16x8 a1 = *(const bf16x8*)&zsb[(16 + lm) * ZP + kt * 32 + q4 * 8];
        acc[0][0] = __builtin_amdgcn_mfma_f32_16x16x32_bf16(a0, wc0, acc[0][0], 0, 0, 0);
        acc[0][1] = __builtin_amdgcn_mfma_f32_16x16x32_bf16(a0, wc1, acc[0][1], 0, 0, 0);
        acc[1][0] = __builtin_amdgcn_mfma_f32_16x16x32_bf16(a1, wc0, acc[1][0], 0, 0, 0);
        acc[1][1] = __builtin_amdgcn_mfma_f32_16x16x32_bf16(a1, wc1, acc[1][1], 0, 0, 0);
        wc0 = wn0; wc1 = wn1;
    }

#pragma unroll
    for (int ntile = 0; ntile < 2; ++ntile) {
        const int col = c0 + ntile * 16 + lm;
        const float bias = b2[col];
#pragma unroll
        for (int mt = 0; mt < 2; ++mt) {
#pragma unroll
            for (int r = 0; r < 4; ++r) {
                const int row  = mt * 16 + q4 * 4 + r;
                const int gidx = (n0b + row) * DIM + col;
                out[gidx] = acc[mt][ntile][r] + bias + bf2f(f[gidx]) + bf2f(h[gidx]);
            }
        }
    }
}

// ---------------------------------------------------------------------------
extern "C" void kernel_launch(void* const* d_in, const int* in_sizes, int n_in,
                              void* d_out, int out_size, void* d_ws, size_t ws_size,
                              hipStream_t stream) {
    const float* ent_feat = (const float*)d_in[0];
    const float* rel_feat = (const float*)d_in[1];
    const int*   src      = (const int*)d_in[2];
    const int*   dst      = (const int*)d_in[3];
    const int*   e_type   = (const int*)d_in[4];
    const float* ln1_g    = (const float*)d_in[5];
    const float* ln1_b    = (const float*)d_in[6];
    const float* W_ent    = (const float*)d_in[7];
    const float* W_rel    = (const float*)d_in[8];
    const float* attn_h   = (const float*)d_in[9];
    const float* attn_t   = (const float*)d_in[10];
    const float* attn_r   = (const float*)d_in[11];
    const float* ln2_g    = (const float*)d_in[12];
    const float* ln2_b    = (const float*)d_in[13];
    const float* W1       = (const float*)d_in[14];
    const float* b1       = (const float*)d_in[15];
    const float* W2       = (const float*)d_in[16];
    const float* b2       = (const float*)d_in[17];
    float* out = (float*)d_out;

    char* ws = (char*)d_ws;
    size_t used = 0;
    auto alloc = [&](size_t bytes) -> char* {
        char* p = ws + used;
        used += (bytes + 255) & ~(size_t)255;
        return p;
    };
    u16*   h       = (u16*)  alloc((size_t)N_NODES * DIM * 2);   // 25.6 MB (bf16)
    u16*   feat0   = (u16*)  alloc((size_t)N_NODES * DIM * 2);   // 25.6 MB
    u16*   fA      = (u16*)  alloc((size_t)N_NODES * DIM * 2);   // 25.6 MB
    u16*   fB      = (u16*)  alloc((size_t)N_NODES * DIM * 2);   // 25.6 MB
    u16*   csr_ab  = (u16*)  alloc((size_t)N_EDGES * NHEAD * 2); // 25.6 MB
    float* eh      = (float*)alloc((size_t)N_NODES * NHEAD * 4); // 3.2 MB
    float* et      = (float*)alloc((size_t)N_NODES * NHEAD * 4); // 3.2 MB
    float* inv_buf = (float*)alloc((size_t)N_NODES * NHEAD * 4); // 3.2 MB
    u32*   csr_se  = (u32*)  alloc((size_t)N_EDGES * 4);         // 6.4 MB
    int*   counts  = (int*)  alloc((size_t)N_NODES * 4);
    int*   offsets = (int*)  alloc((size_t)(N_NODES + 1) * 4);
    int*   cursor  = (int*)  alloc((size_t)N_NODES * 4);
    float* er      = (float*)alloc((size_t)N_REL * NHEAD * 4);
    u16*   W1s     = (u16*)  alloc((size_t)DIM * DFF * 2);
    u16*   W2s     = (u16*)  alloc((size_t)DFF * DIM * 2);
    u16*   Wes     = (u16*)  alloc((size_t)DIM * DIM * 2);
    int*   blk_sums= (int*)  alloc((size_t)NSCANBLK * 4);
    int*   blk_off = (int*)  alloc((size_t)NSCANBLK * 4);

    if (used > ws_size) return;   // diagnostic: absmax == max|ref|

    swz1_k<<<DIM * DFF / 256, 256, 0, stream>>>(W1, W1s);
    swz2_k<<<DFF * DIM / 256, 256, 0, stream>>>(W2, W2s);
    swze_k<<<DIM * DIM / 256, 256, 0, stream>>>(W_ent, Wes);

    ln1_k<<<N_NODES, 128, 0, stream>>>(ent_feat, ln1_g, ln1_b, h);
    proj_k<<<N_NODES / 32, 256, 0, stream>>>(h, Wes, feat0);
    eh_k<<<N_NODES * NHEAD / 256, 256, 0, stream>>>(feat0, attn_h, attn_t, eh, et);
    rel_k<<<N_REL, 128, 0, stream>>>(rel_feat, W_rel, attn_r, er);

    zero_k<<<(N_NODES + 255) / 256, 256, 0, stream>>>(counts, N_NODES);
    count_k<<<(N_EDGES + 255) / 256, 256, 0, stream>>>(dst, counts);
    scan1_k<<<NSCANBLK, 256, 0, stream>>>(counts, offsets, blk_sums, N_NODES);
    scan2_k<<<1, 128, 0, stream>>>(blk_sums, blk_off, offsets, NSCANBLK, N_NODES);
    scan3_k<<<NSCANBLK, 256, 0, stream>>>(offsets, cursor, blk_off, N_NODES);
    scatter_k<<<NECHUNK * NWIN, 256, 0, stream>>>(src, dst, e_type,
                                                  cursor, csr_se);
    softmax_k<<<N_NODES / 4, 256, 0, stream>>>(offsets, csr_se, eh, et, er,
                                               csr_ab, inv_buf);

    // 5 PPR hops: feat0 -> fA -> fB -> fA -> fB -> fA
    hop_k<<<N_NODES / 4, 256, 0, stream>>>(feat0, fA, feat0, offsets, csr_se, csr_ab, inv_buf);
    hop_k<<<N_NODES / 4, 256, 0, stream>>>(fA, fB, feat0, offsets, csr_se, csr_ab, inv_buf);
    hop_k<<<N_NODES / 4, 256, 0, stream>>>(fB, fA, feat0, offsets, csr_se, csr_ab, inv_buf);
    hop_k<<<N_NODES / 4, 256, 0, stream>>>(fA, fB, feat0, offsets, csr_se, csr_ab, inv_buf);
    hop_k<<<N_NODES / 4, 256, 0, stream>>>(fB, fA, feat0, offsets, csr_se, csr_ab, inv_buf);

    // FFN + residuals (MFMA)
    ffn_k<<<N_NODES / 32, 256, 0, stream>>>(fA, h, ln2_g, ln2_b, W1s, b1, W2s, b2,
                                            out);
}